// Round 7
// baseline (319.564 us; speedup 1.0000x reference)
//
#include <hip/hip_runtime.h>
#include <stdint.h>
#include <stddef.h>

typedef unsigned short u16;
typedef unsigned int u32;
typedef __attribute__((ext_vector_type(8))) short s8v;   // 8 bf16 = one MFMA A/B frag
typedef __attribute__((ext_vector_type(4))) short s4v;
typedef __attribute__((ext_vector_type(4))) float f4v;   // MFMA C/D frag / float4

#define D_MODEL 2048
#define NH 16
#define DK 128

__device__ __forceinline__ float b2f(u16 u) {
    union { u32 i; float f; } v; v.i = ((u32)u) << 16; return v.f;
}
__device__ __forceinline__ u16 f2b(float f) {  // RNE; values here always finite
    u32 u = __builtin_bit_cast(u32, f);
    u32 r = (u + 0x7fffu + ((u >> 16) & 1u)) >> 16;
    return (u16)r;
}
__device__ __forceinline__ float fexp2(float x) {        // native v_exp_f32 (base-2)
    return __builtin_amdgcn_exp2f(x);
}
__device__ __forceinline__ f4v mfma16(s8v a, s8v b, f4v c) {
    return __builtin_amdgcn_mfma_f32_16x16x32_bf16(a, b, c, 0, 0, 0);
}
// async global->LDS, 16B/lane. LDS dest must be the WAVE-UNIFORM base; HW adds lane*16.
__device__ __forceinline__ void gload_lds16(const void* g, void* l) {
    __builtin_amdgcn_global_load_lds(
        (const __attribute__((address_space(1))) u32*)(uintptr_t)g,
        (__attribute__((address_space(3))) u32*)(uintptr_t)l, 16, 0, 0);
}

__device__ __forceinline__ void store_out(u16* p, float v)   { *p = f2b(v); }
__device__ __forceinline__ void store_out(float* p, float v) { *p = v; }

// ---------------------------------------------------------------------------
// fp32 -> bf16 conversion pass. grid.y selects segment (0: x, 1..4: weights).
// ---------------------------------------------------------------------------
__global__ __launch_bounds__(256) void cvt_bf16(
    const float* __restrict__ s0, const float* __restrict__ s1,
    const float* __restrict__ s2, const float* __restrict__ s3,
    const float* __restrict__ s4,
    u16* __restrict__ d0, u16* __restrict__ d1, u16* __restrict__ d2,
    u16* __restrict__ d3, u16* __restrict__ d4,
    int n0, int nw)
{
    const int seg = blockIdx.y;
    const float* s = (seg == 0) ? s0 : (seg == 1) ? s1 : (seg == 2) ? s2 : (seg == 3) ? s3 : s4;
    u16*         d = (seg == 0) ? d0 : (seg == 1) ? d1 : (seg == 2) ? d2 : (seg == 3) ? d3 : d4;
    const int    n = (seg == 0) ? n0 : nw;
    int i = (blockIdx.x * 256 + threadIdx.x) * 8;
    if (i >= n) return;
    f4v a = *(const f4v*)(s + i);
    f4v b = *(const f4v*)(s + i + 4);
    s8v o;
    o[0] = (short)f2b(a[0]); o[1] = (short)f2b(a[1]);
    o[2] = (short)f2b(a[2]); o[3] = (short)f2b(a[3]);
    o[4] = (short)f2b(b[0]); o[5] = (short)f2b(b[1]);
    o[6] = (short)f2b(b[2]); o[7] = (short)f2b(b[3]);
    *(s8v*)(d + i) = o;
}

// ---------------------------------------------------------------------------
// GEMM: C[M,N] = A[M,K] * B^T (B given [N,K] row-major). 128x128 tile, BK=64,
// 4 waves of 64x64, T2 XOR swizzle via pre-swizzled global source + swizzled
// frag reads (LDS stays linear for global_load_lds). Unchanged from round 6.
// ---------------------------------------------------------------------------
template<typename OutT>
__global__ __launch_bounds__(256) void gemm_bt3(
    const u16* __restrict__ A,
    const u16* __restrict__ B0, const u16* __restrict__ B1, const u16* __restrict__ B2,
    OutT* __restrict__ C0, OutT* __restrict__ C1, OutT* __restrict__ C2,
    int M, int N, int K)
{
    const int z = blockIdx.z;
    const u16* Bp = (z == 0) ? B0 : (z == 1) ? B1 : B2;
    OutT*      Cp = (z == 0) ? C0 : (z == 1) ? C1 : C2;

    __shared__ short As[128 * 64];   // [row][k] 16 KB, linear (swizzle is in data)
    __shared__ short Bs[128 * 64];

    const int t    = threadIdx.x;
    const int lane = t & 63;
    const int w    = t >> 6;
    const int wm   = (w >> 1) * 64;
    const int wn   = (w & 1) * 64;
    const int m0   = blockIdx.x * 128;
    const int n0   = blockIdx.y * 128;

    const int srow = t >> 3;                         // 0..31
    const int scol = (((t & 7) ^ ((t >> 3) & 7)) * 8);

    f4v acc[4][4];
#pragma unroll
    for (int i = 0; i < 4; i++)
#pragma unroll
        for (int j = 0; j < 4; j++) acc[i][j] = (f4v){0.f, 0.f, 0.f, 0.f};

    const u16* gA = A  + (size_t)(m0 + srow) * K + scol;
    const u16* gB = Bp + (size_t)(n0 + srow) * K + scol;
    char* lA = (char*)As + (size_t)w * 1024;   // wave-uniform LDS bases
    char* lB = (char*)Bs + (size_t)w * 1024;

    const int fr = lane & 15;
    const int g4 = lane >> 4;
    const int xa = fr & 7;                     // read-side XOR term (row&7)

    const size_t rstep = (size_t)32 * K;

    for (int kt = 0; kt < K; kt += 64) {
        __syncthreads();
#pragma unroll
        for (int i = 0; i < 4; i++)
            gload_lds16(gA + (size_t)i * rstep + kt, lA + i * 4096);
#pragma unroll
        for (int i = 0; i < 4; i++)
            gload_lds16(gB + (size_t)i * rstep + kt, lB + i * 4096);
        __syncthreads();

#pragma unroll
        for (int ks = 0; ks < 2; ks++) {
            s8v aF[4], bF[4];
#pragma unroll
            for (int mi = 0; mi < 4; mi++)
                aF[mi] = *(const s8v*)&As[(wm + mi * 16 + fr) * 64 +
                                          (((ks * 4 + g4) ^ xa) * 8)];
#pragma unroll
            for (int ni = 0; ni < 4; ni++)
                bF[ni] = *(const s8v*)&Bs[(wn + ni * 16 + fr) * 64 +
                                          (((ks * 4 + g4) ^ xa) * 8)];
#pragma unroll
            for (int mi = 0; mi < 4; mi++)
#pragma unroll
                for (int ni = 0; ni < 4; ni++)
                    acc[mi][ni] = mfma16(aF[mi], bF[ni], acc[mi][ni]);
        }
    }

    const int rg = (lane >> 4) * 4;
#pragma unroll
    for (int mi = 0; mi < 4; mi++)
#pragma unroll
        for (int ni = 0; ni < 4; ni++) {
            size_t base = (size_t)(m0 + wm + mi * 16 + rg) * N + (n0 + wn + ni * 16 + fr);
#pragma unroll
            for (int r = 0; r < 4; r++)
                store_out(&Cp[base + (size_t)r * N], acc[mi][ni][r]);
        }
}

// ---------------------------------------------------------------------------
// RoPE in-place on Q and K. Folds (1/sqrt(DK))*log2(e) into Q so attention
// softmax can use exp2 directly.
// ---------------------------------------------------------------------------
__global__ void rope_kernel(u32* __restrict__ Q, u32* __restrict__ Kb,
                            const int* __restrict__ pos, int total, int S)
{
    int idx = blockIdx.x * 256 + threadIdx.x;
    if (idx >= total) return;
    int row = idx >> 10;            // 1024 pairs per row
    int pr  = idx & 1023;
    int i   = pr & 63;              // pair index within head
    int s   = row % S;
    float p    = (float)pos[s];
    float freq = __expf((float)i * -0.14391156831212787f);  // 10000^(-i/64)
    float ang  = p * freq;
    float c = cosf(ang), sn = sinf(ang);

    u32 qp = Q[idx];
    float qe = b2f((u16)(qp & 0xffffu)), qo = b2f((u16)(qp >> 16));
    const float sc = 0.12751919968793342f;  // log2(e)/sqrt(128)
    float qe2 = (qe * c - qo * sn) * sc;
    float qo2 = (qe * sn + qo * c) * sc;
    Q[idx] = (u32)f2b(qe2) | ((u32)f2b(qo2) << 16);

    u32 kp = Kb[idx];
    float ke = b2f((u16)(kp & 0xffffu)), ko = b2f((u16)(kp >> 16));
    float ke2 = ke * c - ko * sn;
    float ko2 = ke * sn + ko * c;
    Kb[idx] = (u32)f2b(ke2) | ((u32)f2b(ko2) << 16);
}

// ---------------------------------------------------------------------------
// V transpose: V [b*S + s][o] -> Vt [b][o][s]  (per-batch 2048x2048 transpose)
// ---------------------------------------------------------------------------
__global__ __launch_bounds__(256) void transpose_v(
    const u16* __restrict__ V, u16* __restrict__ Vt, int S)
{
    __shared__ short Tl[64 * 72];
    const int t  = threadIdx.x;
    const int s0 = blockIdx.x * 64;
    const int o0 = blockIdx.y * 64;
    const int b  = blockIdx.z;
    const int r  = t >> 3;            // 0..31
    const int c8 = (t & 7) * 8;
#pragma unroll
    for (int i = 0; i < 2; i++) {
        int row = r + i * 32;         // s within tile
        *(s8v*)&Tl[row * 72 + c8] =
            *(const s8v*)(V + ((size_t)b * S + s0 + row) * D_MODEL + o0 + c8);
    }
    __syncthreads();
#pragma unroll
    for (int i = 0; i < 2; i++) {
        int orow = r + i * 32;        // o within tile
        s8v v;
#pragma unroll
        for (int j = 0; j < 8; j++)
            v[j] = Tl[(c8 + j) * 72 + orow];
        *(s8v*)(Vt + ((size_t)b * D_MODEL + o0 + orow) * S + s0 + c8) = v;
    }
}

// ---------------------------------------------------------------------------
// Causal flash attention v4.
//  - v3 math/swizzles kept; schedule changed for occupancy:
//    single-buffered K/V (2 barriers/iter), LDS 52 KB -> 2 blocks/CU.
//  - Grid 512: one 128-q-tile per block. Dispatch order: first 256 blocks
//    are the LONG tiles (T = ntq-1-a desc), blocks i and i+256 sum to a
//    constant 34 iters -> with round-robin dispatch each CU's two resident
//    blocks are load-balanced. Same-(b,h) blocks keep i%8 const for XCD L2.
//  - T14 reg prefetch: next tile's global loads issued before compute,
//    written to LDS after the post-compute barrier.
// ---------------------------------------------------------------------------
#define AKV 64
#define VP  72
#define PP  72

__global__ __launch_bounds__(256) void attn_kernel(
    const u16* __restrict__ Qg, const u16* __restrict__ Kg,
    const u16* __restrict__ Vtg, u16* __restrict__ Og, int S)
{
    // manual overlay: K [64][128] | Vt [128][72] | Ps [4][32*72]; the final
    // O staging [128][128] (32 KB) reuses K+Vt after a barrier.
    __shared__ short smem[8192 + 9216 + 9216];   // 53248 B
    short* Kl = smem;                 // [64][128] swizzled
    short* Vl = smem + 8192;          // [128][VP]
    short* Pl = smem + 8192 + 9216;   // [4][32*PP]
    short* OL = smem;                 // [128][128] epilogue

    const int t    = threadIdx.x;
    const int lane = t & 63;
    const int w    = t >> 6;
    const int fr   = lane & 15;
    const int g4   = lane >> 4;
    const int xfr  = (fr & 7) << 3;

    // block decode: i<half -> long tiles (T desc), i>=half -> short (T asc)
    const int ntq = S / 128;               // 16
    const int nbh = NH * 2;                // 32 (b in {0,1})
    const int i_  = blockIdx.x;
    const int hfm = (ntq / 2) * nbh;       // 256
    const int j   = (i_ < hfm) ? i_ : (i_ - hfm);
    const int a   = j / nbh;
    const int bh  = j % nbh;
    const int T   = (i_ < hfm) ? (ntq - 1 - a) : a;
    const int h   = bh & 15;
    const int b   = bh >> 4;

    const int q0  = T * 128;
    const int nkv = 2 * T + 2;

    const u16* Qb  = Qg + ((size_t)b * S) * D_MODEL + (size_t)h * DK;
    const u16* Kb  = Kg + ((size_t)b * S) * D_MODEL + (size_t)h * DK;
    const u16* Vtb = Vtg + ((size_t)b * D_MODEL + (size_t)h * DK) * S;
    u16*       Ob  = Og + ((size_t)b * S) * D_MODEL + (size_t)h * DK;

    // staging maps
    const int krow = t >> 4;               // K tile row base (0..15, +16c)
    const int kc8  = (t & 15) * 8;
    const int kxor = (krow & 7) << 3;
    const int vd   = t >> 3;               // V^T tile d base (0..31, +32c)
    const int vk8  = (t & 7) * 8;

    // Q frags direct from global (once)
    s8v qf[2][4];
#pragma unroll
    for (int s = 0; s < 2; s++)
#pragma unroll
        for (int ks = 0; ks < 4; ks++)
            qf[s][ks] = *(const s8v*)(Qb +
                (size_t)(q0 + s * 64 + w * 16 + fr) * D_MODEL + ks * 32 + g4 * 8);

    // tile 0 -> regs -> LDS
    s8v kreg[4], vreg[4];
#pragma unroll
    for (int c = 0; c < 4; c++) {
        kreg[c] = *(const s8v*)(Kb + (size_t)(krow + 16 * c) * D_MODEL + kc8);
        vreg[c] = *(const s8v*)(Vtb + (size_t)(32 * c + vd) * S + vk8);
    }
#pragma unroll
    for (int c = 0; c < 4; c++)
        *(s8v*)&Kl[(krow + 16 * c) * 128 + (kc8 ^ kxor)] = kreg[c];
#pragma unroll
    for (int c = 0; c < 4; c++)
        *(s8v*)&Vl[(32 * c + vd) * VP + vk8] = vreg[c];
    __syncthreads();

    float m_st[2] = {-1e30f, -1e30f};
    float l_st[2] = {0.f, 0.f};
    f4v accO[2][8];
#pragma unroll
    for (int s = 0; s < 2; s++)
#pragma unroll
        for (int df = 0; df < 8; df++) accO[s][df] = (f4v){0.f, 0.f, 0.f, 0.f};

    for (int kt = 0; kt < nkv; kt++) {
        const int  kv0  = kt * AKV;
        const bool last = (kt + 1 == nkv);
        const bool do0  = (kv0 < q0 + 64);   // sub0 has any unmasked kv

        // T14: issue next tile's global loads now, consume after compute
        if (!last) {
            const size_t kvn = (size_t)(kt + 1) * AKV;
#pragma unroll
            for (int c = 0; c < 4; c++) {
                kreg[c] = *(const s8v*)(Kb + (kvn + krow + 16 * c) * D_MODEL + kc8);
                vreg[c] = *(const s8v*)(Vtb + (size_t)(32 * c + vd) * S + kvn + vk8);
            }
        }

        // S^T = K * Q^T for both q-subtiles (shared kfr)
        f4v sacc[2][4];
#pragma unroll
        for (int s = 0; s < 2; s++)
#pragma unroll
            for (int i = 0; i < 4; i++) sacc[s][i] = (f4v){0.f, 0.f, 0.f, 0.f};
#pragma unroll
        for (int ks = 0; ks < 4; ks++) {
            s8v kfr[4];
#pragma unroll
            for (int kf = 0; kf < 4; kf++)
                kfr[kf] = *(const s8v*)&Kl[(kf * 16 + fr) * 128 +
                                           ((ks * 32 + g4 * 8) ^ xfr)];
            if (do0) {
#pragma unroll
                for (int kf = 0; kf < 4; kf++)
                    sacc[0][kf] = mfma16(kfr[kf], qf[0][ks], sacc[0][kf]);
            }
#pragma unroll
            for (int kf = 0; kf < 4; kf++)
                sacc[1][kf] = mfma16(kfr[kf], qf[1][ks], sacc[1][kf]);
        }

        // per-sub online softmax (exp2 domain; per-lane q col = fr)
#pragma unroll
        for (int s = 0; s < 2; s++) {
            if (s == 0 && !do0) continue;
            const int qg = q0 + s * 64 + w * 16 + fr;
            if (kv0 == q0 + s * 64) {        // diagonal tile for this sub
#pragma unroll
                for (int kf = 0; kf < 4; kf++)
#pragma unroll
                    for (int r = 0; r < 4; r++)
                        if (kv0 + kf * 16 + g4 * 4 + r > qg)
                            sacc[s][kf][r] = -1e30f;
            }
            float rm = -1e30f;
#pragma unroll
            for (int kf = 0; kf < 4; kf++)
                rm = fmaxf(rm, fmaxf(fmaxf(sacc[s][kf][0], sacc[s][kf][1]),
                                     fmaxf(sacc[s][kf][2], sacc[s][kf][3])));
            rm = fmaxf(rm, __shfl_xor(rm, 16));
            rm = fmaxf(rm, __shfl_xor(rm, 32));
            if (__any(rm > m_st[s])) {       // exact defer: P <= 1 otherwise
                float mn   = fmaxf(m_st[s], rm);
                float corr = fexp2(m_st[s] - mn);
                l_st[s] *= corr;
#pragma unroll
                for (int df = 0; df < 8; df++) {
                    accO[s][df][0] *= corr; accO[s][df][1] *= corr;
                    accO[s][df][2] *= corr; accO[s][df][3] *= corr;
                }
                m_st[s] = mn;
            }
            float rsum = 0.f;
#pragma unroll
            for (int kf = 0; kf < 4; kf++) {
                float p0 = fexp2(sacc[s][kf][0] - m_st[s]);
                float p1 = fexp2(sacc[s][kf][1] - m_st[s]);
                float p2 = fexp2(sacc[s][kf][2] - m_st[s]);
                float p3 = fexp2(sacc[s][kf][3] - m_st[s]);
                rsum += (p0 + p1) + (p2 + p3);
                s4v pk;
                pk[0] = (short)f2b(p0); pk[1] = (short)f2b(p1);
                pk[2] = (short)f2b(p2); pk[3] = (short)f2b(p3);
                *(s4v*)&Pl[(size_t)w * (32 * PP) + (s * 16 + fr) * PP + kf * 16 + g4 * 4] = pk;
            }
            rsum += __shfl_xor(rsum, 16);
            rsum += __shfl_xor(rsum, 32);
            l_st[s] += rsum;
        }

        // O^T += V^T * P^T (shared vf across subs; same-wave Pl RAW ok)
#pragma unroll
        for (int ks = 0; ks < 2; ks++) {
            s8v pf0, pf1;
            if (do0) pf0 = *(const s8v*)&Pl[(size_t)w * (32 * PP) + fr * PP + ks * 32 + g4 * 8];
            pf1 = *(const s8v*)&Pl[(size_t)w * (32 * PP) + (16 + fr) * PP + ks * 32 + g4 * 8];
#pragma unroll
            for (int df = 0; df < 8; df++) {
                s8v vf = *(const s8v*)&Vl[(df * 16 + fr) * VP + ks * 32 + g4 * 8];
                if (do0) accO[0][df] = mfma16(vf, pf0, accO[0][df]);
                accO[1][df] = mfma16(vf, pf1, accO[1][df]);
            }
        }

        // publish prefetched tile (single buffer: post-compute barrier)
        if (!last) {
            __syncthreads();             // all waves done reading Kl/Vl
#pragma unroll
            for (int c = 0; c < 4; c++)
                *(s8v*)&Kl[(krow + 16 * c) * 128 + (kc8 ^ kxor)] = kreg[c];
#pragma unroll
            for (int c = 0; c < 4; c++)
                *(s8v*)&Vl[(32 * c + vd) * VP + vk8] = vreg[c];
            __syncthreads();
        }
    }

    // normalize, transpose O^T -> O through OL ([128][128] over K+V), store
    __syncthreads();                     // all waves done with Kl/Vl/Pl
#pragma unroll
    for (int s = 0; s < 2; s++) {
        float inv = 1.f / l_st[s];
#pragma unroll
        for (int df = 0; df < 8; df++) {
            s4v ov;
            ov[0] = (short)f2b(accO[s][df][0] * inv);
            ov[1] = (short)f2b(accO[s][df][1] * inv);
            ov[2] = (short)f2b(accO[s][df][2] * inv);
            ov[3] = (short)f2b(accO[s][df][3] * inv);
            *(s4v*)&OL[(s * 64 + w * 16 + fr) * 128 + ((df * 16 + g4 * 4) ^ xfr)] = ov;
        }
    }
    __syncthreads();
#pragma unroll
    for (int i = 0; i < 8; i++) {
        int row = i * 16 + (t >> 4);
        int ch  = (t & 15) * 8;
        s8v v = *(const s8v*)&OL[row * 128 + (ch ^ ((row & 7) << 3))];
        *(s8v*)(Ob + (size_t)(q0 + row) * D_MODEL + ch) = v;
    }
}

// ---------------------------------------------------------------------------
extern "C" void kernel_launch(void* const* d_in, const int* in_sizes, int n_in,
                              void* d_out, int out_size, void* d_ws, size_t ws_size,
                              hipStream_t stream)
{
    const float* x  = (const float*)d_in[0];
    const float* wq = (const float*)d_in[1];
    const float* wk = (const float*)d_in[2];
    const float* wv = (const float*)d_in[3];
    const float* wo = (const float*)d_in[4];
    const int*   tp = (const int*)d_in[5];

    const int S  = in_sizes[5];
    const int BS = in_sizes[0] / D_MODEL;   // B*S rows (4096)
    const int Bn = BS / S;
    const int NW = D_MODEL * D_MODEL;
    const int NX = BS * D_MODEL;

    // ws (u16 elems): [Q][K][V -> O][Xb -> Vt][Wq][Wk][Wv][Wo] = 96 MB
    u16* Qw  = (u16*)d_ws;
    u16* Kw  = Qw + (size_t)NX;
    u16* Vw  = Kw + (size_t)NX;             // V; reused as attention output O
    u16* Xb  = Vw + (size_t)NX;             // x bf16; reused as V^T
    u16* Wqb = Xb + (size_t)NX;
    u16* Wkb = Wqb + (size_t)NW;
    u16* Wvb = Wkb + (size_t)NW;
    u16* Wob = Wvb + (size_t)NW;

    {
        dim3 g((NX / 8 + 255) / 256, 5);
        cvt_bf16<<<g, 256, 0, stream>>>(x, wq, wk, wv, wo,
                                        Xb, Wqb, Wkb, Wvb, Wob, NX, NW);
    }

    // Q,K,V projections
    dim3 gq(BS / 128, D_MODEL / 128, 3);
    gemm_bt3<u16><<<gq, 256, 0, stream>>>(Xb, Wqb, Wkb, Wvb, Qw, Kw, Vw,
                                          BS, D_MODEL, D_MODEL);

    // RoPE on Q,K (in place); V^T into Xb region (x is dead after QKV GEMM)
    int total = BS * (D_MODEL / 2);
    rope_kernel<<<(total + 255) / 256, 256, 0, stream>>>((u32*)Qw, (u32*)Kw, tp, total, S);
    transpose_v<<<dim3(S / 64, D_MODEL / 64, Bn), 256, 0, stream>>>(Vw, Xb, S);

    // causal flash attention: O (bf16) into the V region (V dead after transpose)
    attn_kernel<<<dim3((S / 128) * NH * Bn, 1, 1), 256, 0, stream>>>(Qw, Kw, Xb, Vw, S);

    // output projection -> fp32 d_out
    dim3 go(BS / 128, D_MODEL / 128, 1);
    gemm_bt3<float><<<go, 256, 0, stream>>>(Vw, Wob, Wob, Wob,
                                            (float*)d_out, (float*)d_out, (float*)d_out,
                                            BS, D_MODEL, D_MODEL);
}

// Round 8
// 285.785 us; speedup vs baseline: 1.1182x; 1.1182x over previous
//
#include <hip/hip_runtime.h>
#include <stdint.h>
#include <stddef.h>

typedef unsigned short u16;
typedef unsigned int u32;
typedef __attribute__((ext_vector_type(8))) short s8v;   // 8 bf16 = one MFMA A/B frag
typedef __attribute__((ext_vector_type(4))) short s4v;
typedef __attribute__((ext_vector_type(4))) float f4v;   // MFMA C/D frag / float4

#define D_MODEL 2048
#define NH 16
#define DK 128

__device__ __forceinline__ float b2f(u16 u) {
    union { u32 i; float f; } v; v.i = ((u32)u) << 16; return v.f;
}
__device__ __forceinline__ u16 f2b(float f) {  // RNE; values here always finite
    u32 u = __builtin_bit_cast(u32, f);
    u32 r = (u + 0x7fffu + ((u >> 16) & 1u)) >> 16;
    return (u16)r;
}
__device__ __forceinline__ float fexp2(float x) {        // native v_exp_f32 (base-2)
    return __builtin_amdgcn_exp2f(x);
}
__device__ __forceinline__ f4v mfma16(s8v a, s8v b, f4v c) {
    return __builtin_amdgcn_mfma_f32_16x16x32_bf16(a, b, c, 0, 0, 0);
}
// async global->LDS, 16B/lane. LDS dest must be the WAVE-UNIFORM base; HW adds lane*16.
__device__ __forceinline__ void gload_lds16(const void* g, void* l) {
    __builtin_amdgcn_global_load_lds(
        (const __attribute__((address_space(1))) u32*)(uintptr_t)g,
        (__attribute__((address_space(3))) u32*)(uintptr_t)l, 16, 0, 0);
}

__device__ __forceinline__ void store_out(u16* p, float v)   { *p = f2b(v); }
__device__ __forceinline__ void store_out(float* p, float v) { *p = v; }

// ---------------------------------------------------------------------------
// fp32 -> bf16 conversion pass. grid.y selects segment (0: x, 1..4: weights).
// ---------------------------------------------------------------------------
__global__ __launch_bounds__(256) void cvt_bf16(
    const float* __restrict__ s0, const float* __restrict__ s1,
    const float* __restrict__ s2, const float* __restrict__ s3,
    const float* __restrict__ s4,
    u16* __restrict__ d0, u16* __restrict__ d1, u16* __restrict__ d2,
    u16* __restrict__ d3, u16* __restrict__ d4,
    int n0, int nw)
{
    const int seg = blockIdx.y;
    const float* s = (seg == 0) ? s0 : (seg == 1) ? s1 : (seg == 2) ? s2 : (seg == 3) ? s3 : s4;
    u16*         d = (seg == 0) ? d0 : (seg == 1) ? d1 : (seg == 2) ? d2 : (seg == 3) ? d3 : d4;
    const int    n = (seg == 0) ? n0 : nw;
    int i = (blockIdx.x * 256 + threadIdx.x) * 8;
    if (i >= n) return;
    f4v a = *(const f4v*)(s + i);
    f4v b = *(const f4v*)(s + i + 4);
    s8v o;
    o[0] = (short)f2b(a[0]); o[1] = (short)f2b(a[1]);
    o[2] = (short)f2b(a[2]); o[3] = (short)f2b(a[3]);
    o[4] = (short)f2b(b[0]); o[5] = (short)f2b(b[1]);
    o[6] = (short)f2b(b[2]); o[7] = (short)f2b(b[3]);
    *(s8v*)(d + i) = o;
}

// ---------------------------------------------------------------------------
// GEMM v2: C[M,N] = A[M,K] * B^T.  256x128 tile, BK=64, 512 threads = 8 waves
// (4M x 2N, each 64x64 out). T2 swizzle (pre-swizzled global source, linear
// LDS for global_load_lds, XOR'd frag reads). T4 counted-vmcnt pipeline:
// double-buffered LDS, raw s_barrier, vmcnt(6) steady state (tile t+1's 6
// loads stay in flight across barriers), vmcnt(0) only at the last tile.
// Schedule per tile t: [vmcnt(6)][barrier][compute 32 MFMA/wave][barrier]
// [issue 6 gloads for tile t+2 into buf[t&1]].  WAR-safe: prefetch into
// buf[t&1] is issued only after the post-compute barrier; RAW-safe: each
// wave's vmcnt + the pre-compute barrier => all waves' loads landed.
// ---------------------------------------------------------------------------
template<typename OutT>
__global__ __launch_bounds__(512) void gemm_bt3(
    const u16* __restrict__ A,
    const u16* __restrict__ B0, const u16* __restrict__ B1, const u16* __restrict__ B2,
    OutT* __restrict__ C0, OutT* __restrict__ C1, OutT* __restrict__ C2,
    int M, int N, int K)
{
    const int z = blockIdx.z;
    const u16* Bp = (z == 0) ? B0 : (z == 1) ? B1 : B2;
    OutT*      Cp = (z == 0) ? C0 : (z == 1) ? C1 : C2;

    __shared__ short As[2 * 256 * 64];   // 64 KB, linear (swizzle in data)
    __shared__ short Bs[2 * 128 * 64];   // 32 KB

    const int t    = threadIdx.x;
    const int lane = t & 63;
    const int w    = t >> 6;             // 0..7
    const int wr   = w >> 1;             // 0..3 (64-row band)
    const int wc   = w & 1;              // 0..1 (64-col band)
    const int m0   = blockIdx.x * 256;
    const int n0   = blockIdx.y * 128;

    // staging map: issue i covers rows i*64 + (t>>3), 16B slot t&7 (linear in
    // LDS); global source slot = (t&7) ^ (row&7) carries the swizzle.
    const int srow = t >> 3;                          // 0..63
    const int scol = (((t & 7) ^ ((t >> 3) & 7)) * 8);

    const u16* gA = A  + (size_t)(m0 + srow) * K + scol;
    const u16* gB = Bp + (size_t)(n0 + srow) * K + scol;
    char* lA = (char*)As + (size_t)w * 1024;          // wave-uniform LDS bases
    char* lB = (char*)Bs + (size_t)w * 1024;
    const size_t rstep = (size_t)64 * K;

    const int fr = lane & 15;
    const int g4 = lane >> 4;
    const int xa = fr & 7;                            // read-side XOR (row&7)

    f4v acc[4][4];
#pragma unroll
    for (int i = 0; i < 4; i++)
#pragma unroll
        for (int j = 0; j < 4; j++) acc[i][j] = (f4v){0.f, 0.f, 0.f, 0.f};

    const int NT = K / 64;               // 32

    // STAGE(tile kt -> buffer p): 4 A-issues + 2 B-issues, fixed order
    auto STAGE = [&](int p, int kt) {
        const u16* a = gA + (size_t)kt * 64;
        const u16* b = gB + (size_t)kt * 64;
        char* la = lA + p * 32768;
        char* lb = lB + p * 16384;
#pragma unroll
        for (int i = 0; i < 4; i++)
            gload_lds16(a + (size_t)i * rstep, la + i * 8192);
#pragma unroll
        for (int i = 0; i < 2; i++)
            gload_lds16(b + (size_t)i * rstep, lb + i * 8192);
    };

    STAGE(0, 0);
    if (NT > 1) STAGE(1, 1);

    for (int kt = 0; kt < NT; kt++) {
        const int p = kt & 1;
        if (kt < NT - 1) asm volatile("s_waitcnt vmcnt(6)" ::: "memory");
        else             asm volatile("s_waitcnt vmcnt(0)" ::: "memory");
        asm volatile("s_barrier" ::: "memory");

        const short* Ab = As + p * 16384;
        const short* Bb = Bs + p * 8192;
#pragma unroll
        for (int ks = 0; ks < 2; ks++) {
            const int sl = ((ks * 4 + g4) ^ xa) * 8;
            s8v aF[4], bF[4];
#pragma unroll
            for (int mi = 0; mi < 4; mi++)
                aF[mi] = *(const s8v*)&Ab[(wr * 64 + mi * 16 + fr) * 64 + sl];
#pragma unroll
            for (int ni = 0; ni < 4; ni++)
                bF[ni] = *(const s8v*)&Bb[(wc * 64 + ni * 16 + fr) * 64 + sl];
            __builtin_amdgcn_s_setprio(1);
#pragma unroll
            for (int mi = 0; mi < 4; mi++)
#pragma unroll
                for (int ni = 0; ni < 4; ni++)
                    acc[mi][ni] = mfma16(aF[mi], bF[ni], acc[mi][ni]);
            __builtin_amdgcn_s_setprio(0);
        }

        asm volatile("s_barrier" ::: "memory");
        if (kt + 2 < NT) STAGE(p, kt + 2);
    }

    // epilogue: C row = (lane>>4)*4+reg, col = lane&15  (m89-verified layout)
    const int rg = g4 * 4;
#pragma unroll
    for (int mi = 0; mi < 4; mi++)
#pragma unroll
        for (int ni = 0; ni < 4; ni++) {
            size_t base = (size_t)(m0 + wr * 64 + mi * 16 + rg) * N
                        + (n0 + wc * 64 + ni * 16 + fr);
#pragma unroll
            for (int r = 0; r < 4; r++)
                store_out(&Cp[base + (size_t)r * N], acc[mi][ni][r]);
        }
}

// ---------------------------------------------------------------------------
// RoPE in-place on Q and K. Folds (1/sqrt(DK))*log2(e) into Q so attention
// softmax can use exp2 directly.
// ---------------------------------------------------------------------------
__global__ void rope_kernel(u32* __restrict__ Q, u32* __restrict__ Kb,
                            const int* __restrict__ pos, int total, int S)
{
    int idx = blockIdx.x * 256 + threadIdx.x;
    if (idx >= total) return;
    int row = idx >> 10;            // 1024 pairs per row
    int pr  = idx & 1023;
    int i   = pr & 63;              // pair index within head
    int s   = row % S;
    float p    = (float)pos[s];
    float freq = __expf((float)i * -0.14391156831212787f);  // 10000^(-i/64)
    float ang  = p * freq;
    float c = cosf(ang), sn = sinf(ang);

    u32 qp = Q[idx];
    float qe = b2f((u16)(qp & 0xffffu)), qo = b2f((u16)(qp >> 16));
    const float sc = 0.12751919968793342f;  // log2(e)/sqrt(128)
    float qe2 = (qe * c - qo * sn) * sc;
    float qo2 = (qe * sn + qo * c) * sc;
    Q[idx] = (u32)f2b(qe2) | ((u32)f2b(qo2) << 16);

    u32 kp = Kb[idx];
    float ke = b2f((u16)(kp & 0xffffu)), ko = b2f((u16)(kp >> 16));
    float ke2 = ke * c - ko * sn;
    float ko2 = ke * sn + ko * c;
    Kb[idx] = (u32)f2b(ke2) | ((u32)f2b(ko2) << 16);
}

// ---------------------------------------------------------------------------
// V transpose: V [b*S + s][o] -> Vt [b][o][s]  (per-batch 2048x2048 transpose)
// ---------------------------------------------------------------------------
__global__ __launch_bounds__(256) void transpose_v(
    const u16* __restrict__ V, u16* __restrict__ Vt, int S)
{
    __shared__ short Tl[64 * 72];
    const int t  = threadIdx.x;
    const int s0 = blockIdx.x * 64;
    const int o0 = blockIdx.y * 64;
    const int b  = blockIdx.z;
    const int r  = t >> 3;            // 0..31
    const int c8 = (t & 7) * 8;
#pragma unroll
    for (int i = 0; i < 2; i++) {
        int row = r + i * 32;         // s within tile
        *(s8v*)&Tl[row * 72 + c8] =
            *(const s8v*)(V + ((size_t)b * S + s0 + row) * D_MODEL + o0 + c8);
    }
    __syncthreads();
#pragma unroll
    for (int i = 0; i < 2; i++) {
        int orow = r + i * 32;        // o within tile
        s8v v;
#pragma unroll
        for (int j = 0; j < 8; j++)
            v[j] = Tl[(c8 + j) * 72 + orow];
        *(s8v*)(Vt + ((size_t)b * D_MODEL + o0 + orow) * S + s0 + c8) = v;
    }
}

// ---------------------------------------------------------------------------
// Causal flash attention v3 (round-6 version, reverted verbatim: in-block
// pairing for guaranteed load balance; dispatch-order independent).
// ---------------------------------------------------------------------------
#define AKV 64
#define VP  72
#define PP  72

__global__ __launch_bounds__(256) void attn_kernel(
    const u16* __restrict__ Qg, const u16* __restrict__ Kg,
    const u16* __restrict__ Vtg, u16* __restrict__ Og, int S)
{
    __shared__ short Kbuf[2][64 * 128];    // 32 KB (also O[128][128] staging)
    __shared__ short Vbuf[2][128 * VP];    // 36 KB  V^T tiles [d][kv]
    __shared__ short Ps[4][32 * PP];       // 18 KB  per-wave P [q][kv]

    const int t    = threadIdx.x;
    const int lane = t & 63;
    const int w    = t >> 6;
    const int fr   = lane & 15;
    const int g4   = lane >> 4;
    const int xfr  = (fr & 7) << 3;

    // XCD-bijective decode (grid.x = 256 = 8 pairs x 32 (b,h) groups)
    const int d_ = blockIdx.x;
    const int tt = d_ >> 3;
    const int G  = ((tt & 3) << 3) | (d_ & 7);
    const int p  = tt >> 2;
    const int h  = G & 15;
    const int b  = G >> 4;
    const int ntq = S / 128;               // 16

    const u16* Qb  = Qg + ((size_t)b * S) * D_MODEL + (size_t)h * DK;
    const u16* Kb  = Kg + ((size_t)b * S) * D_MODEL + (size_t)h * DK;
    const u16* Vtb = Vtg + ((size_t)b * D_MODEL + (size_t)h * DK) * S;
    u16*       Ob  = Og + ((size_t)b * S) * D_MODEL + (size_t)h * DK;

    // staging maps
    const int krow = t >> 4;               // K tile row base (0..15, +16c)
    const int kc8  = (t & 15) * 8;
    const int kxor = (krow & 7) << 3;
    const int vd   = t >> 3;               // V^T tile d base (0..31, +32c)
    const int vk8  = (t & 7) * 8;

    for (int half = 0; half < 2; half++) {
        const int T   = half ? (ntq - 1 - p) : p;
        const int q0  = T * 128;
        const int nkv = 2 * T + 2;

        // Q frags direct from global (once per half)
        s8v qf[2][4];
#pragma unroll
        for (int s = 0; s < 2; s++)
#pragma unroll
            for (int ks = 0; ks < 4; ks++)
                qf[s][ks] = *(const s8v*)(Qb +
                    (size_t)(q0 + s * 64 + w * 16 + fr) * D_MODEL + ks * 32 + g4 * 8);

        // tile 0 -> regs
        s8v kreg[4], vreg[4];
#pragma unroll
        for (int c = 0; c < 4; c++) {
            kreg[c] = *(const s8v*)(Kb + (size_t)(krow + 16 * c) * D_MODEL + kc8);
            vreg[c] = *(const s8v*)(Vtb + (size_t)(32 * c + vd) * S + vk8);
        }
        __syncthreads();                   // prev half's O-staging reads done
#pragma unroll
        for (int c = 0; c < 4; c++)
            *(s8v*)&Kbuf[0][(krow + 16 * c) * 128 + (kc8 ^ kxor)] = kreg[c];
#pragma unroll
        for (int c = 0; c < 4; c++)
            *(s8v*)&Vbuf[0][(32 * c + vd) * VP + vk8] = vreg[c];
        __syncthreads();

        float m_st[2] = {-1e30f, -1e30f};
        float l_st[2] = {0.f, 0.f};
        f4v accO[2][8];
#pragma unroll
        for (int s = 0; s < 2; s++)
#pragma unroll
            for (int df = 0; df < 8; df++) accO[s][df] = (f4v){0.f, 0.f, 0.f, 0.f};

        for (int kt = 0; kt < nkv; kt++) {
            const int  kv0  = kt * AKV;
            const int  buf  = kt & 1;
            const bool last = (kt + 1 == nkv);
            const bool do0  = (kv0 < q0 + 64);   // sub0 has any unmasked kv

            // T14: issue next tile's loads now, consume after compute
            if (!last) {
                const size_t kvn = (size_t)(kt + 1) * AKV;
#pragma unroll
                for (int c = 0; c < 4; c++) {
                    kreg[c] = *(const s8v*)(Kb + (kvn + krow + 16 * c) * D_MODEL + kc8);
                    vreg[c] = *(const s8v*)(Vtb + (size_t)(32 * c + vd) * S + kvn + vk8);
                }
            }

            // S^T = K * Q^T for both q-subtiles (shared kfr)
            f4v sacc[2][4];
#pragma unroll
            for (int s = 0; s < 2; s++)
#pragma unroll
                for (int i = 0; i < 4; i++) sacc[s][i] = (f4v){0.f, 0.f, 0.f, 0.f};
#pragma unroll
            for (int ks = 0; ks < 4; ks++) {
                s8v kfr[4];
#pragma unroll
                for (int kf = 0; kf < 4; kf++)
                    kfr[kf] = *(const s8v*)&Kbuf[buf][(kf * 16 + fr) * 128 +
                                                     ((ks * 32 + g4 * 8) ^ xfr)];
                if (do0) {
#pragma unroll
                    for (int kf = 0; kf < 4; kf++)
                        sacc[0][kf] = mfma16(kfr[kf], qf[0][ks], sacc[0][kf]);
                }
#pragma unroll
                for (int kf = 0; kf < 4; kf++)
                    sacc[1][kf] = mfma16(kfr[kf], qf[1][ks], sacc[1][kf]);
            }

            // per-sub online softmax (exp2 domain; per-lane q col = fr)
#pragma unroll
            for (int s = 0; s < 2; s++) {
                if (s == 0 && !do0) continue;
                const int qg = q0 + s * 64 + w * 16 + fr;
                if (kv0 == q0 + s * 64) {        // diagonal tile for this sub
#pragma unroll
                    for (int kf = 0; kf < 4; kf++)
#pragma unroll
                        for (int r = 0; r < 4; r++)
                            if (kv0 + kf * 16 + g4 * 4 + r > qg)
                                sacc[s][kf][r] = -1e30f;
                }
                float rm = -1e30f;
#pragma unroll
                for (int kf = 0; kf < 4; kf++)
                    rm = fmaxf(rm, fmaxf(fmaxf(sacc[s][kf][0], sacc[s][kf][1]),
                                         fmaxf(sacc[s][kf][2], sacc[s][kf][3])));
                rm = fmaxf(rm, __shfl_xor(rm, 16));
                rm = fmaxf(rm, __shfl_xor(rm, 32));
                if (__any(rm > m_st[s])) {       // exact defer: P <= 1 otherwise
                    float mn   = fmaxf(m_st[s], rm);
                    float corr = fexp2(m_st[s] - mn);
                    l_st[s] *= corr;
#pragma unroll
                    for (int df = 0; df < 8; df++) {
                        accO[s][df][0] *= corr; accO[s][df][1] *= corr;
                        accO[s][df][2] *= corr; accO[s][df][3] *= corr;
                    }
                    m_st[s] = mn;
                }
                float rsum = 0.f;
#pragma unroll
                for (int kf = 0; kf < 4; kf++) {
                    float p0 = fexp2(sacc[s][kf][0] - m_st[s]);
                    float p1 = fexp2(sacc[s][kf][1] - m_st[s]);
                    float p2 = fexp2(sacc[s][kf][2] - m_st[s]);
                    float p3 = fexp2(sacc[s][kf][3] - m_st[s]);
                    rsum += (p0 + p1) + (p2 + p3);
                    s4v pk;
                    pk[0] = (short)f2b(p0); pk[1] = (short)f2b(p1);
                    pk[2] = (short)f2b(p2); pk[3] = (short)f2b(p3);
                    *(s4v*)&Ps[w][(s * 16 + fr) * PP + kf * 16 + g4 * 4] = pk;
                }
                rsum += __shfl_xor(rsum, 16);
                rsum += __shfl_xor(rsum, 32);
                l_st[s] += rsum;
            }

            // O^T += V^T * P^T (shared vf across subs; same-wave Ps RAW ok)
#pragma unroll
            for (int ks = 0; ks < 2; ks++) {
                s8v pf0, pf1;
                if (do0) pf0 = *(const s8v*)&Ps[w][fr * PP + ks * 32 + g4 * 8];
                pf1 = *(const s8v*)&Ps[w][(16 + fr) * PP + ks * 32 + g4 * 8];
#pragma unroll
                for (int df = 0; df < 8; df++) {
                    s8v vf = *(const s8v*)&Vbuf[buf][(df * 16 + fr) * VP +
                                                     ks * 32 + g4 * 8];
                    if (do0) accO[0][df] = mfma16(vf, pf0, accO[0][df]);
                    accO[1][df] = mfma16(vf, pf1, accO[1][df]);
                }
            }

            // write prefetched tile to the other buffer
            if (!last) {
#pragma unroll
                for (int c = 0; c < 4; c++)
                    *(s8v*)&Kbuf[buf ^ 1][(krow + 16 * c) * 128 + (kc8 ^ kxor)] = kreg[c];
#pragma unroll
                for (int c = 0; c < 4; c++)
                    *(s8v*)&Vbuf[buf ^ 1][(32 * c + vd) * VP + vk8] = vreg[c];
            }
            __syncthreads();
        }

        // normalize, transpose O^T -> O through Kbuf ([128][128]), store
        short* OL = (short*)&Kbuf[0][0];
#pragma unroll
        for (int s = 0; s < 2; s++) {
            float inv = 1.f / l_st[s];
#pragma unroll
            for (int df = 0; df < 8; df++) {
                s4v ov;
                ov[0] = (short)f2b(accO[s][df][0] * inv);
                ov[1] = (short)f2b(accO[s][df][1] * inv);
                ov[2] = (short)f2b(accO[s][df][2] * inv);
                ov[3] = (short)f2b(accO[s][df][3] * inv);
                *(s4v*)&OL[(s * 64 + w * 16 + fr) * 128 + ((df * 16 + g4 * 4) ^ xfr)] = ov;
            }
        }
        __syncthreads();
#pragma unroll
        for (int i = 0; i < 8; i++) {
            int row = i * 16 + (t >> 4);
            int ch  = (t & 15) * 8;
            s8v v = *(const s8v*)&OL[row * 128 + (ch ^ ((row & 7) << 3))];
            *(s8v*)(Ob + (size_t)(q0 + row) * D_MODEL + ch) = v;
        }
    }
}

// ---------------------------------------------------------------------------
extern "C" void kernel_launch(void* const* d_in, const int* in_sizes, int n_in,
                              void* d_out, int out_size, void* d_ws, size_t ws_size,
                              hipStream_t stream)
{
    const float* x  = (const float*)d_in[0];
    const float* wq = (const float*)d_in[1];
    const float* wk = (const float*)d_in[2];
    const float* wv = (const float*)d_in[3];
    const float* wo = (const float*)d_in[4];
    const int*   tp = (const int*)d_in[5];

    const int S  = in_sizes[5];
    const int BS = in_sizes[0] / D_MODEL;   // B*S rows (4096)
    const int Bn = BS / S;
    const int NW = D_MODEL * D_MODEL;
    const int NX = BS * D_MODEL;

    // ws (u16 elems): [Q][K][V -> O][Xb -> Vt][Wq][Wk][Wv][Wo] = 96 MB
    u16* Qw  = (u16*)d_ws;
    u16* Kw  = Qw + (size_t)NX;
    u16* Vw  = Kw + (size_t)NX;             // V; reused as attention output O
    u16* Xb  = Vw + (size_t)NX;             // x bf16; reused as V^T
    u16* Wqb = Xb + (size_t)NX;
    u16* Wkb = Wqb + (size_t)NW;
    u16* Wvb = Wkb + (size_t)NW;
    u16* Wob = Wvb + (size_t)NW;

    {
        dim3 g((NX / 8 + 255) / 256, 5);
        cvt_bf16<<<g, 256, 0, stream>>>(x, wq, wk, wv, wo,
                                        Xb, Wqb, Wkb, Wvb, Wob, NX, NW);
    }

    // Q,K,V projections: 256x128 tiles -> 16*16*3 = 768 blocks = 3 full CU-rounds
    dim3 gq(BS / 256, D_MODEL / 128, 3);
    gemm_bt3<u16><<<gq, 512, 0, stream>>>(Xb, Wqb, Wkb, Wvb, Qw, Kw, Vw,
                                          BS, D_MODEL, D_MODEL);

    // RoPE on Q,K (in place); V^T into Xb region (x is dead after QKV GEMM)
    int total = BS * (D_MODEL / 2);
    rope_kernel<<<(total + 255) / 256, 256, 0, stream>>>((u32*)Qw, (u32*)Kw, tp, total, S);
    transpose_v<<<dim3(S / 64, D_MODEL / 64, Bn), 256, 0, stream>>>(Vw, Xb, S);

    // causal flash attention: O (bf16) into the V region (V dead after transpose)
    attn_kernel<<<dim3((S / 256) * NH * Bn, 1, 1), 256, 0, stream>>>(Qw, Kw, Xb, Vw, S);

    // output projection -> fp32 d_out: 16*16 = 256 blocks = 1 full round
    dim3 go(BS / 256, D_MODEL / 128, 1);
    gemm_bt3<float><<<go, 512, 0, stream>>>(Vw, Wob, Wob, Wob,
                                            (float*)d_out, (float*)d_out, (float*)d_out,
                                            BS, D_MODEL, D_MODEL);
}

// Round 9
// 282.806 us; speedup vs baseline: 1.1300x; 1.0105x over previous
//
#include <hip/hip_runtime.h>
#include <stdint.h>
#include <stddef.h>

typedef unsigned short u16;
typedef unsigned int u32;
typedef __attribute__((ext_vector_type(8))) short s8v;   // 8 bf16 = one MFMA A/B frag
typedef __attribute__((ext_vector_type(4))) short s4v;
typedef __attribute__((ext_vector_type(4))) float f4v;   // MFMA C/D frag / float4

#define D_MODEL 2048
#define NH 16
#define DK 128

__device__ __forceinline__ float b2f(u16 u) {
    union { u32 i; float f; } v; v.i = ((u32)u) << 16; return v.f;
}
__device__ __forceinline__ u16 f2b(float f) {  // RNE; values here always finite
    u32 u = __builtin_bit_cast(u32, f);
    u32 r = (u + 0x7fffu + ((u >> 16) & 1u)) >> 16;
    return (u16)r;
}
__device__ __forceinline__ float fexp2(float x) {        // native v_exp_f32 (base-2)
    return __builtin_amdgcn_exp2f(x);
}
__device__ __forceinline__ f4v mfma16(s8v a, s8v b, f4v c) {
    return __builtin_amdgcn_mfma_f32_16x16x32_bf16(a, b, c, 0, 0, 0);
}
// async global->LDS, 16B/lane. LDS dest must be the WAVE-UNIFORM base; HW adds lane*16.
__device__ __forceinline__ void gload_lds16(const void* g, void* l) {
    __builtin_amdgcn_global_load_lds(
        (const __attribute__((address_space(1))) u32*)(uintptr_t)g,
        (__attribute__((address_space(3))) u32*)(uintptr_t)l, 16, 0, 0);
}

__device__ __forceinline__ void store_out(u16* p, float v)   { *p = f2b(v); }
__device__ __forceinline__ void store_out(float* p, float v) { *p = v; }

#define SBAR()   asm volatile("s_barrier" ::: "memory")
#define VMCNT(n) asm volatile("s_waitcnt vmcnt(" #n ")" ::: "memory")

// ---------------------------------------------------------------------------
// fp32 -> bf16 conversion pass. grid.y selects segment (0: x, 1..4: weights).
// ---------------------------------------------------------------------------
__global__ __launch_bounds__(256) void cvt_bf16(
    const float* __restrict__ s0, const float* __restrict__ s1,
    const float* __restrict__ s2, const float* __restrict__ s3,
    const float* __restrict__ s4,
    u16* __restrict__ d0, u16* __restrict__ d1, u16* __restrict__ d2,
    u16* __restrict__ d3, u16* __restrict__ d4,
    int n0, int nw)
{
    const int seg = blockIdx.y;
    const float* s = (seg == 0) ? s0 : (seg == 1) ? s1 : (seg == 2) ? s2 : (seg == 3) ? s3 : s4;
    u16*         d = (seg == 0) ? d0 : (seg == 1) ? d1 : (seg == 2) ? d2 : (seg == 3) ? d3 : d4;
    const int    n = (seg == 0) ? n0 : nw;
    int i = (blockIdx.x * 256 + threadIdx.x) * 8;
    if (i >= n) return;
    f4v a = *(const f4v*)(s + i);
    f4v b = *(const f4v*)(s + i + 4);
    s8v o;
    o[0] = (short)f2b(a[0]); o[1] = (short)f2b(a[1]);
    o[2] = (short)f2b(a[2]); o[3] = (short)f2b(a[3]);
    o[4] = (short)f2b(b[0]); o[5] = (short)f2b(b[1]);
    o[6] = (short)f2b(b[2]); o[7] = (short)f2b(b[3]);
    *(s8v*)(d + i) = o;
}

// ---------------------------------------------------------------------------
// GEMM 8-phase (m201 template): C = A[M,K] * B^T, BM=BN=256, BK=64, 512 thr
// = 8 waves (2M x 4N, wave-tile 128x64). LDS 128 KB: 2 tile-slots x (A 32KB +
// B 32KB). T2 swizzle: pre-swizzled GLOBAL source column (LDS linear for
// global_load_lds), XOR'd frag reads. Per iter = 2 K-tiles = 8 phases; each
// phase: {ds_read 4-8 b128 | stage 1 half-tile (2 gloads) | [vmcnt(4) at
// P1/P4/P5/P8] | s_barrier | 16 MFMA setprio | s_barrier}.
// Stage rotation (iter i; t0=2i slot0, t1=2i+1 slot1):
//   P1:B(t1,h1) P2:A(t1,h0) P3:A(t1,h1) P4:B(t0+2,h0)
//   P5:B(t0+2,h1) P6:A(t0+2,h0) P7:A(t0+2,h1) P8:B(t1+2,h0)
// WAR: every slot is overwritten >=1 phase after its last ds_read completes.
// RAW: vmcnt(4)-before-barrier certifies all-but-newest-4 loads landed for
// ALL waves crossing that barrier; each phase's reads dep only on certified
// stages (verified phase-by-phase). Last iter clamps prefetch tile index to a
// valid address (counts uniform; data never read).
// ---------------------------------------------------------------------------
__global__ __launch_bounds__(512) void gemm8(
    const u16* __restrict__ A,
    const u16* __restrict__ B0, const u16* __restrict__ B1, const u16* __restrict__ B2,
    u16* __restrict__ C0, u16* __restrict__ C1, u16* __restrict__ C2,
    int M, int N, int K)
{
    const int z = blockIdx.z;
    const u16* Bp = (z == 0) ? B0 : (z == 1) ? B1 : B2;
    u16*       Cp = (z == 0) ? C0 : (z == 1) ? C1 : C2;

    __shared__ short As[2 * 256 * 64];   // 64 KB (2 tile-slots)
    __shared__ short Bs[2 * 256 * 64];   // 64 KB

    const int t    = threadIdx.x;
    const int lane = t & 63;
    const int w    = t >> 6;             // 0..7
    const int wr   = w >> 2;             // 0..1  (128-row band)
    const int wc   = w & 3;              // 0..3  (64-col band)
    const int m0   = blockIdx.x * 256;
    const int n0   = blockIdx.y * 256;

    // staging: issue j covers rows j*64 + (t>>3); 16B slot t&7 linear in LDS;
    // global source slot (t&7)^(row&7) carries the swizzle.
    const int srow = t >> 3;                          // 0..63
    const int scol = (((t & 7) ^ ((t >> 3) & 7)) * 8);

    const u16* gA = A  + (size_t)(m0 + srow) * K + scol;
    const u16* gB = Bp + (size_t)(n0 + srow) * K + scol;
    char* lA = (char*)As + (size_t)w * 1024;          // wave-uniform bases
    char* lB = (char*)Bs + (size_t)w * 1024;
    const size_t rstep = (size_t)64 * K;

    const int fr = lane & 15;
    const int g4 = lane >> 4;
    const int xa = fr & 7;

    f4v acc[8][4];
#pragma unroll
    for (int i = 0; i < 8; i++)
#pragma unroll
        for (int j = 0; j < 4; j++) acc[i][j] = (f4v){0.f, 0.f, 0.f, 0.f};

    // half-tile stagers: 2 issues each (issue pair {2h, 2h+1})
    auto stageA = [&](int p, int kt, int h) {
        const u16* g = gA + (size_t)kt * 64;
#pragma unroll
        for (int j = 0; j < 2; j++)
            gload_lds16(g + (size_t)(2 * h + j) * rstep,
                        lA + p * 32768 + (2 * h + j) * 8192);
    };
    auto stageB = [&](int p, int kt, int h) {
        const u16* g = gB + (size_t)kt * 64;
#pragma unroll
        for (int j = 0; j < 2; j++)
            gload_lds16(g + (size_t)(2 * h + j) * rstep,
                        lB + p * 32768 + (2 * h + j) * 8192);
    };
    auto loadA = [&](int p, int mh, int ks, s8v* aF) {
        const short* base = As + p * 16384;
        const int sl = ((ks * 4 + g4) ^ xa) * 8;
#pragma unroll
        for (int mi = 0; mi < 4; mi++)
            aF[mi] = *(const s8v*)&base[(wr * 128 + mh * 64 + mi * 16 + fr) * 64 + sl];
    };
    auto loadB = [&](int p, int ks, s8v* bF) {
        const short* base = Bs + p * 16384;
        const int sl = ((ks * 4 + g4) ^ xa) * 8;
#pragma unroll
        for (int ni = 0; ni < 4; ni++)
            bF[ni] = *(const s8v*)&base[(wc * 64 + ni * 16 + fr) * 64 + sl];
    };
    auto mfc = [&](int mh, s8v* aF, s8v* bF) {
        __builtin_amdgcn_s_setprio(1);
#pragma unroll
        for (int mi = 0; mi < 4; mi++)
#pragma unroll
            for (int ni = 0; ni < 4; ni++)
                acc[mh * 4 + mi][ni] = mfma16(aF[mi], bF[ni], acc[mh * 4 + mi][ni]);
        __builtin_amdgcn_s_setprio(0);
    };

    const int NT = K / 64;               // 32
    const int NI = NT / 2;               // 16

    // prologue: full tile 0 (slot 0) + B(1,h0); certify tile 0 (newest 2 allowed)
    stageB(0, 0, 0); stageB(0, 0, 1); stageA(0, 0, 0); stageA(0, 0, 1);
    stageB(1, 1, 0);
    VMCNT(2);
    SBAR();

    for (int i = 0; i < NI; i++) {
        const int k1 = 2 * i + 1;
        const int k2 = (2 * i + 2 < NT) ? 2 * i + 2 : 0;   // clamp: addr valid, data unread
        const int k3 = (2 * i + 3 < NT) ? 2 * i + 3 : 1;
        s8v aF[4], bF[4];

        // P1: t0 (mh0,ks0)
        loadA(0, 0, 0, aF); loadB(0, 0, bF);
        stageB(1, k1, 1);
        VMCNT(4); SBAR();
        mfc(0, aF, bF);
        SBAR();
        // P2: t0 (mh1,ks0) — B reuse
        loadA(0, 1, 0, aF);
        stageA(1, k1, 0);
        SBAR();
        mfc(1, aF, bF);
        SBAR();
        // P3: t0 (mh0,ks1)
        loadA(0, 0, 1, aF); loadB(0, 1, bF);
        stageA(1, k1, 1);
        SBAR();
        mfc(0, aF, bF);
        SBAR();
        // P4: t0 (mh1,ks1)
        loadA(0, 1, 1, aF);
        stageB(0, k2, 0);
        VMCNT(4); SBAR();
        mfc(1, aF, bF);
        SBAR();
        // P5: t1 (mh0,ks0)
        loadA(1, 0, 0, aF); loadB(1, 0, bF);
        stageB(0, k2, 1);
        VMCNT(4); SBAR();
        mfc(0, aF, bF);
        SBAR();
        // P6: t1 (mh1,ks0)
        loadA(1, 1, 0, aF);
        stageA(0, k2, 0);
        SBAR();
        mfc(1, aF, bF);
        SBAR();
        // P7: t1 (mh0,ks1)
        loadA(1, 0, 1, aF); loadB(1, 1, bF);
        stageA(0, k2, 1);
        SBAR();
        mfc(0, aF, bF);
        SBAR();
        // P8: t1 (mh1,ks1)
        loadA(1, 1, 1, aF);
        stageB(1, k3, 0);
        VMCNT(4); SBAR();
        mfc(1, aF, bF);
        SBAR();
    }
    VMCNT(0);

    // epilogue: C row = (lane>>4)*4+reg, col = lane&15 per 16x16 frag
    const int rg = g4 * 4;
#pragma unroll
    for (int mit = 0; mit < 8; mit++)
#pragma unroll
        for (int ni = 0; ni < 4; ni++) {
            size_t base = (size_t)(m0 + wr * 128 + mit * 16 + rg) * N
                        + (n0 + wc * 64 + ni * 16 + fr);
#pragma unroll
            for (int r = 0; r < 4; r++)
                Cp[base + (size_t)r * N] = f2b(acc[mit][ni][r]);
        }
}

// ---------------------------------------------------------------------------
// GEMM 128x128 (round-6 m97-structure): used for the wo projection (256
// blocks = 1 perfect CU-round). BK=64, 4 waves, T2 swizzle, 2-barrier loop.
// ---------------------------------------------------------------------------
template<typename OutT>
__global__ __launch_bounds__(256) void gemm_bt3(
    const u16* __restrict__ A, const u16* __restrict__ Bp,
    OutT* __restrict__ Cp, int M, int N, int K)
{
    __shared__ short As[128 * 64];
    __shared__ short Bs[128 * 64];

    const int t    = threadIdx.x;
    const int lane = t & 63;
    const int w    = t >> 6;
    const int wm   = (w >> 1) * 64;
    const int wn   = (w & 1) * 64;
    const int m0   = blockIdx.x * 128;
    const int n0   = blockIdx.y * 128;

    const int srow = t >> 3;
    const int scol = (((t & 7) ^ ((t >> 3) & 7)) * 8);

    f4v acc[4][4];
#pragma unroll
    for (int i = 0; i < 4; i++)
#pragma unroll
        for (int j = 0; j < 4; j++) acc[i][j] = (f4v){0.f, 0.f, 0.f, 0.f};

    const u16* gA = A  + (size_t)(m0 + srow) * K + scol;
    const u16* gB = Bp + (size_t)(n0 + srow) * K + scol;
    char* lA = (char*)As + (size_t)w * 1024;
    char* lB = (char*)Bs + (size_t)w * 1024;

    const int fr = lane & 15;
    const int g4 = lane >> 4;
    const int xa = fr & 7;

    const size_t rstep = (size_t)32 * K;

    for (int kt = 0; kt < K; kt += 64) {
        __syncthreads();
#pragma unroll
        for (int i = 0; i < 4; i++)
            gload_lds16(gA + (size_t)i * rstep + kt, lA + i * 4096);
#pragma unroll
        for (int i = 0; i < 4; i++)
            gload_lds16(gB + (size_t)i * rstep + kt, lB + i * 4096);
        __syncthreads();

#pragma unroll
        for (int ks = 0; ks < 2; ks++) {
            s8v aF[4], bF[4];
#pragma unroll
            for (int mi = 0; mi < 4; mi++)
                aF[mi] = *(const s8v*)&As[(wm + mi * 16 + fr) * 64 +
                                          (((ks * 4 + g4) ^ xa) * 8)];
#pragma unroll
            for (int ni = 0; ni < 4; ni++)
                bF[ni] = *(const s8v*)&Bs[(wn + ni * 16 + fr) * 64 +
                                          (((ks * 4 + g4) ^ xa) * 8)];
#pragma unroll
            for (int mi = 0; mi < 4; mi++)
#pragma unroll
                for (int ni = 0; ni < 4; ni++)
                    acc[mi][ni] = mfma16(aF[mi], bF[ni], acc[mi][ni]);
        }
    }

    const int rg = (lane >> 4) * 4;
#pragma unroll
    for (int mi = 0; mi < 4; mi++)
#pragma unroll
        for (int ni = 0; ni < 4; ni++) {
            size_t base = (size_t)(m0 + wm + mi * 16 + rg) * N + (n0 + wn + ni * 16 + fr);
#pragma unroll
            for (int r = 0; r < 4; r++)
                store_out(&Cp[base + (size_t)r * N], acc[mi][ni][r]);
        }
}

// ---------------------------------------------------------------------------
// RoPE in-place on Q and K. Folds (1/sqrt(DK))*log2(e) into Q so attention
// softmax can use exp2 directly.
// ---------------------------------------------------------------------------
__global__ void rope_kernel(u32* __restrict__ Q, u32* __restrict__ Kb,
                            const int* __restrict__ pos, int total, int S)
{
    int idx = blockIdx.x * 256 + threadIdx.x;
    if (idx >= total) return;
    int row = idx >> 10;            // 1024 pairs per row
    int pr  = idx & 1023;
    int i   = pr & 63;              // pair index within head
    int s   = row % S;
    float p    = (float)pos[s];
    float freq = __expf((float)i * -0.14391156831212787f);  // 10000^(-i/64)
    float ang  = p * freq;
    float c = cosf(ang), sn = sinf(ang);

    u32 qp = Q[idx];
    float qe = b2f((u16)(qp & 0xffffu)), qo = b2f((u16)(qp >> 16));
    const float sc = 0.12751919968793342f;  // log2(e)/sqrt(128)
    float qe2 = (qe * c - qo * sn) * sc;
    float qo2 = (qe * sn + qo * c) * sc;
    Q[idx] = (u32)f2b(qe2) | ((u32)f2b(qo2) << 16);

    u32 kp = Kb[idx];
    float ke = b2f((u16)(kp & 0xffffu)), ko = b2f((u16)(kp >> 16));
    float ke2 = ke * c - ko * sn;
    float ko2 = ke * sn + ko * c;
    Kb[idx] = (u32)f2b(ke2) | ((u32)f2b(ko2) << 16);
}

// ---------------------------------------------------------------------------
// V transpose: V [b*S + s][o] -> Vt [b][o][s]
// ---------------------------------------------------------------------------
__global__ __launch_bounds__(256) void transpose_v(
    const u16* __restrict__ V, u16* __restrict__ Vt, int S)
{
    __shared__ short Tl[64 * 72];
    const int t  = threadIdx.x;
    const int s0 = blockIdx.x * 64;
    const int o0 = blockIdx.y * 64;
    const int b  = blockIdx.z;
    const int r  = t >> 3;
    const int c8 = (t & 7) * 8;
#pragma unroll
    for (int i = 0; i < 2; i++) {
        int row = r + i * 32;
        *(s8v*)&Tl[row * 72 + c8] =
            *(const s8v*)(V + ((size_t)b * S + s0 + row) * D_MODEL + o0 + c8);
    }
    __syncthreads();
#pragma unroll
    for (int i = 0; i < 2; i++) {
        int orow = r + i * 32;
        s8v v;
#pragma unroll
        for (int j = 0; j < 8; j++)
            v[j] = Tl[(c8 + j) * 72 + orow];
        *(s8v*)(Vt + ((size_t)b * D_MODEL + o0 + orow) * S + s0 + c8) = v;
    }
}

// ---------------------------------------------------------------------------
// Causal flash attention v3 (round-6 version, unchanged).
// ---------------------------------------------------------------------------
#define AKV 64
#define VP  72
#define PP  72

__global__ __launch_bounds__(256) void attn_kernel(
    const u16* __restrict__ Qg, const u16* __restrict__ Kg,
    const u16* __restrict__ Vtg, u16* __restrict__ Og, int S)
{
    __shared__ short Kbuf[2][64 * 128];
    __shared__ short Vbuf[2][128 * VP];
    __shared__ short Ps[4][32 * PP];

    const int t    = threadIdx.x;
    const int lane = t & 63;
    const int w    = t >> 6;
    const int fr   = lane & 15;
    const int g4   = lane >> 4;
    const int xfr  = (fr & 7) << 3;

    const int d_ = blockIdx.x;
    const int tt = d_ >> 3;
    const int G  = ((tt & 3) << 3) | (d_ & 7);
    const int p  = tt >> 2;
    const int h  = G & 15;
    const int b  = G >> 4;
    const int ntq = S / 128;

    const u16* Qb  = Qg + ((size_t)b * S) * D_MODEL + (size_t)h * DK;
    const u16* Kb  = Kg + ((size_t)b * S) * D_MODEL + (size_t)h * DK;
    const u16* Vtb = Vtg + ((size_t)b * D_MODEL + (size_t)h * DK) * S;
    u16*       Ob  = Og + ((size_t)b * S) * D_MODEL + (size_t)h * DK;

    const int krow = t >> 4;
    const int kc8  = (t & 15) * 8;
    const int kxor = (krow & 7) << 3;
    const int vd   = t >> 3;
    const int vk8  = (t & 7) * 8;

    for (int half = 0; half < 2; half++) {
        const int T   = half ? (ntq - 1 - p) : p;
        const int q0  = T * 128;
        const int nkv = 2 * T + 2;

        s8v qf[2][4];
#pragma unroll
        for (int s = 0; s < 2; s++)
#pragma unroll
            for (int ks = 0; ks < 4; ks++)
                qf[s][ks] = *(const s8v*)(Qb +
                    (size_t)(q0 + s * 64 + w * 16 + fr) * D_MODEL + ks * 32 + g4 * 8);

        s8v kreg[4], vreg[4];
#pragma unroll
        for (int c = 0; c < 4; c++) {
            kreg[c] = *(const s8v*)(Kb + (size_t)(krow + 16 * c) * D_MODEL + kc8);
            vreg[c] = *(const s8v*)(Vtb + (size_t)(32 * c + vd) * S + vk8);
        }
        __syncthreads();
#pragma unroll
        for (int c = 0; c < 4; c++)
            *(s8v*)&Kbuf[0][(krow + 16 * c) * 128 + (kc8 ^ kxor)] = kreg[c];
#pragma unroll
        for (int c = 0; c < 4; c++)
            *(s8v*)&Vbuf[0][(32 * c + vd) * VP + vk8] = vreg[c];
        __syncthreads();

        float m_st[2] = {-1e30f, -1e30f};
        float l_st[2] = {0.f, 0.f};
        f4v accO[2][8];
#pragma unroll
        for (int s = 0; s < 2; s++)
#pragma unroll
            for (int df = 0; df < 8; df++) accO[s][df] = (f4v){0.f, 0.f, 0.f, 0.f};

        for (int kt = 0; kt < nkv; kt++) {
            const int  kv0  = kt * AKV;
            const int  buf  = kt & 1;
            const bool last = (kt + 1 == nkv);
            const bool do0  = (kv0 < q0 + 64);

            if (!last) {
                const size_t kvn = (size_t)(kt + 1) * AKV;
#pragma unroll
                for (int c = 0; c < 4; c++) {
                    kreg[c] = *(const s8v*)(Kb + (kvn + krow + 16 * c) * D_MODEL + kc8);
                    vreg[c] = *(const s8v*)(Vtb + (size_t)(32 * c + vd) * S + kvn + vk8);
                }
            }

            f4v sacc[2][4];
#pragma unroll
            for (int s = 0; s < 2; s++)
#pragma unroll
                for (int i = 0; i < 4; i++) sacc[s][i] = (f4v){0.f, 0.f, 0.f, 0.f};
#pragma unroll
            for (int ks = 0; ks < 4; ks++) {
                s8v kfr[4];
#pragma unroll
                for (int kf = 0; kf < 4; kf++)
                    kfr[kf] = *(const s8v*)&Kbuf[buf][(kf * 16 + fr) * 128 +
                                                     ((ks * 32 + g4 * 8) ^ xfr)];
                if (do0) {
#pragma unroll
                    for (int kf = 0; kf < 4; kf++)
                        sacc[0][kf] = mfma16(kfr[kf], qf[0][ks], sacc[0][kf]);
                }
#pragma unroll
                for (int kf = 0; kf < 4; kf++)
                    sacc[1][kf] = mfma16(kfr[kf], qf[1][ks], sacc[1][kf]);
            }

#pragma unroll
            for (int s = 0; s < 2; s++) {
                if (s == 0 && !do0) continue;
                const int qg = q0 + s * 64 + w * 16 + fr;
                if (kv0 == q0 + s * 64) {
#pragma unroll
                    for (int kf = 0; kf < 4; kf++)
#pragma unroll
                        for (int r = 0; r < 4; r++)
                            if (kv0 + kf * 16 + g4 * 4 + r > qg)
                                sacc[s][kf][r] = -1e30f;
                }
                float rm = -1e30f;
#pragma unroll
                for (int kf = 0; kf < 4; kf++)
                    rm = fmaxf(rm, fmaxf(fmaxf(sacc[s][kf][0], sacc[s][kf][1]),
                                         fmaxf(sacc[s][kf][2], sacc[s][kf][3])));
                rm = fmaxf(rm, __shfl_xor(rm, 16));
                rm = fmaxf(rm, __shfl_xor(rm, 32));
                if (__any(rm > m_st[s])) {
                    float mn   = fmaxf(m_st[s], rm);
                    float corr = fexp2(m_st[s] - mn);
                    l_st[s] *= corr;
#pragma unroll
                    for (int df = 0; df < 8; df++) {
                        accO[s][df][0] *= corr; accO[s][df][1] *= corr;
                        accO[s][df][2] *= corr; accO[s][df][3] *= corr;
                    }
                    m_st[s] = mn;
                }
                float rsum = 0.f;
#pragma unroll
                for (int kf = 0; kf < 4; kf++) {
                    float p0 = fexp2(sacc[s][kf][0] - m_st[s]);
                    float p1 = fexp2(sacc[s][kf][1] - m_st[s]);
                    float p2 = fexp2(sacc[s][kf][2] - m_st[s]);
                    float p3 = fexp2(sacc[s][kf][3] - m_st[s]);
                    rsum += (p0 + p1) + (p2 + p3);
                    s4v pk;
                    pk[0] = (short)f2b(p0); pk[1] = (short)f2b(p1);
                    pk[2] = (short)f2b(p2); pk[3] = (short)f2b(p3);
                    *(s4v*)&Ps[w][(s * 16 + fr) * PP + kf * 16 + g4 * 4] = pk;
                }
                rsum += __shfl_xor(rsum, 16);
                rsum += __shfl_xor(rsum, 32);
                l_st[s] += rsum;
            }

#pragma unroll
            for (int ks = 0; ks < 2; ks++) {
                s8v pf0, pf1;
                if (do0) pf0 = *(const s8v*)&Ps[w][fr * PP + ks * 32 + g4 * 8];
                pf1 = *(const s8v*)&Ps[w][(16 + fr) * PP + ks * 32 + g4 * 8];
#pragma unroll
                for (int df = 0; df < 8; df++) {
                    s8v vf = *(const s8v*)&Vbuf[buf][(df * 16 + fr) * VP +
                                                     ks * 32 + g4 * 8];
                    if (do0) accO[0][df] = mfma16(vf, pf0, accO[0][df]);
                    accO[1][df] = mfma16(vf, pf1, accO[1][df]);
                }
            }

            if (!last) {
#pragma unroll
                for (int c = 0; c < 4; c++)
                    *(s8v*)&Kbuf[buf ^ 1][(krow + 16 * c) * 128 + (kc8 ^ kxor)] = kreg[c];
#pragma unroll
                for (int c = 0; c < 4; c++)
                    *(s8v*)&Vbuf[buf ^ 1][(32 * c + vd) * VP + vk8] = vreg[c];
            }
            __syncthreads();
        }

        short* OL = (short*)&Kbuf[0][0];
#pragma unroll
        for (int s = 0; s < 2; s++) {
            float inv = 1.f / l_st[s];
#pragma unroll
            for (int df = 0; df < 8; df++) {
                s4v ov;
                ov[0] = (short)f2b(accO[s][df][0] * inv);
                ov[1] = (short)f2b(accO[s][df][1] * inv);
                ov[2] = (short)f2b(accO[s][df][2] * inv);
                ov[3] = (short)f2b(accO[s][df][3] * inv);
                *(s4v*)&OL[(s * 64 + w * 16 + fr) * 128 + ((df * 16 + g4 * 4) ^ xfr)] = ov;
            }
        }
        __syncthreads();
#pragma unroll
        for (int i = 0; i < 8; i++) {
            int row = i * 16 + (t >> 4);
            int ch  = (t & 15) * 8;
            s8v v = *(const s8v*)&OL[row * 128 + (ch ^ ((row & 7) << 3))];
            *(s8v*)(Ob + (size_t)(q0 + row) * D_MODEL + ch) = v;
        }
    }
}

// ---------------------------------------------------------------------------
extern "C" void kernel_launch(void* const* d_in, const int* in_sizes, int n_in,
                              void* d_out, int out_size, void* d_ws, size_t ws_size,
                              hipStream_t stream)
{
    const float* x  = (const float*)d_in[0];
    const float* wq = (const float*)d_in[1];
    const float* wk = (const float*)d_in[2];
    const float* wv = (const float*)d_in[3];
    const float* wo = (const float*)d_in[4];
    const int*   tp = (const int*)d_in[5];

    const int S  = in_sizes[5];
    const int BS = in_sizes[0] / D_MODEL;   // B*S rows (4096)
    const int Bn = BS / S;
    const int NW = D_MODEL * D_MODEL;
    const int NX = BS * D_MODEL;

    // ws (u16 elems): [Q][K][V -> O][Xb -> Vt][Wq][Wk][Wv][Wo] = 96 MB
    u16* Qw  = (u16*)d_ws;
    u16* Kw  = Qw + (size_t)NX;
    u16* Vw  = Kw + (size_t)NX;             // V; reused as attention output O
    u16* Xb  = Vw + (size_t)NX;             // x bf16; reused as V^T
    u16* Wqb = Xb + (size_t)NX;
    u16* Wkb = Wqb + (size_t)NW;
    u16* Wvb = Wkb + (size_t)NW;
    u16* Wob = Wvb + (size_t)NW;

    {
        dim3 g((NX / 8 + 255) / 256, 5);
        cvt_bf16<<<g, 256, 0, stream>>>(x, wq, wk, wv, wo,
                                        Xb, Wqb, Wkb, Wvb, Wob, NX, NW);
    }

    // Q,K,V projections: 8-phase 256^2 kernel, 16*8*3 = 384 blocks
    dim3 gq(BS / 256, D_MODEL / 256, 3);
    gemm8<<<gq, 512, 0, stream>>>(Xb, Wqb, Wkb, Wvb, Qw, Kw, Vw,
                                  BS, D_MODEL, D_MODEL);

    // RoPE on Q,K (in place); V^T into Xb region (x is dead after QKV GEMM)
    int total = BS * (D_MODEL / 2);
    rope_kernel<<<(total + 255) / 256, 256, 0, stream>>>((u32*)Qw, (u32*)Kw, tp, total, S);
    transpose_v<<<dim3(S / 64, D_MODEL / 64, Bn), 256, 0, stream>>>(Vw, Xb, S);

    // causal flash attention: O (bf16) into the V region
    attn_kernel<<<dim3((S / 256) * NH * Bn, 1, 1), 256, 0, stream>>>(Qw, Kw, Xb, Vw, S);

    // output projection -> fp32 d_out: 128^2 kernel, 32*16 = 512 blocks
    dim3 go(BS / 128, D_MODEL / 128, 1);
    gemm_bt3<float><<<go, 256, 0, stream>>>(Vw, Wob, (float*)d_out,
                                            BS, D_MODEL, D_MODEL);
}

// Round 11
// 250.451 us; speedup vs baseline: 1.2760x; 1.1292x over previous
//
#include <hip/hip_runtime.h>
#include <stdint.h>
#include <stddef.h>

typedef unsigned short u16;
typedef unsigned int u32;
typedef __attribute__((ext_vector_type(8))) short s8v;   // 8 bf16 = one MFMA A/B frag
typedef __attribute__((ext_vector_type(4))) short s4v;
typedef __attribute__((ext_vector_type(4))) float f4v;   // MFMA C/D frag / float4

#define D_MODEL 2048
#define NH 16
#define DK 128

__device__ __forceinline__ float b2f(u16 u) {
    union { u32 i; float f; } v; v.i = ((u32)u) << 16; return v.f;
}
__device__ __forceinline__ u16 f2b(float f) {  // RNE; values here always finite
    u32 u = __builtin_bit_cast(u32, f);
    u32 r = (u + 0x7fffu + ((u >> 16) & 1u)) >> 16;
    return (u16)r;
}
__device__ __forceinline__ float fexp2(float x) {        // native v_exp_f32 (base-2)
    return __builtin_amdgcn_exp2f(x);
}
__device__ __forceinline__ f4v mfma16(s8v a, s8v b, f4v c) {
    return __builtin_amdgcn_mfma_f32_16x16x32_bf16(a, b, c, 0, 0, 0);
}
// async global->LDS, 16B/lane. LDS dest must be the WAVE-UNIFORM base; HW adds lane*16.
__device__ __forceinline__ void gload_lds16(const void* g, void* l) {
    __builtin_amdgcn_global_load_lds(
        (const __attribute__((address_space(1))) u32*)(uintptr_t)g,
        (__attribute__((address_space(3))) u32*)(uintptr_t)l, 16, 0, 0);
}

__device__ __forceinline__ void store_out(u16* p, float v)   { *p = f2b(v); }
__device__ __forceinline__ void store_out(float* p, float v) { *p = v; }

#define SBAR()   asm volatile("s_barrier" ::: "memory")
#define VMCNT(n) asm volatile("s_waitcnt vmcnt(" #n ")" ::: "memory")

// ---------------------------------------------------------------------------
// fp32 -> bf16 conversion pass. grid.y selects segment (0: x, 1..4: weights).
// ---------------------------------------------------------------------------
__global__ __launch_bounds__(256) void cvt_bf16(
    const float* __restrict__ s0, const float* __restrict__ s1,
    const float* __restrict__ s2, const float* __restrict__ s3,
    const float* __restrict__ s4,
    u16* __restrict__ d0, u16* __restrict__ d1, u16* __restrict__ d2,
    u16* __restrict__ d3, u16* __restrict__ d4,
    int n0, int nw)
{
    const int seg = blockIdx.y;
    const float* s = (seg == 0) ? s0 : (seg == 1) ? s1 : (seg == 2) ? s2 : (seg == 3) ? s3 : s4;
    u16*         d = (seg == 0) ? d0 : (seg == 1) ? d1 : (seg == 2) ? d2 : (seg == 3) ? d3 : d4;
    const int    n = (seg == 0) ? n0 : nw;
    int i = (blockIdx.x * 256 + threadIdx.x) * 8;
    if (i >= n) return;
    f4v a = *(const f4v*)(s + i);
    f4v b = *(const f4v*)(s + i + 4);
    s8v o;
    o[0] = (short)f2b(a[0]); o[1] = (short)f2b(a[1]);
    o[2] = (short)f2b(a[2]); o[3] = (short)f2b(a[3]);
    o[4] = (short)f2b(b[0]); o[5] = (short)f2b(b[1]);
    o[6] = (short)f2b(b[2]); o[7] = (short)f2b(b[3]);
    *(s8v*)(d + i) = o;
}

// ---------------------------------------------------------------------------
// GEMM 8-phase, BM=256 x BN=128, BK=64, 512 thr = 8 waves (4M x 2N, 64x64
// wave-tile). LDS 144 KB: THREE slots x (A 32KB + B 16KB). T2 swizzle via
// pre-swizzled global source + XOR'd frag reads (LDS linear for
// global_load_lds).
// Schedule (iter i; s0/s1/s2 rotate): read s0 = tile 2i (P1-P4), s1 = tile
// 2i+1 (P5-P8). Stage tile 2i+2 -> s2 at P1/P2/P3 (A0,A1,B); tile 2i+3 -> s0
// at P5/P6/P7. VMCNT(6) ONLY at P4 and P8:
//   P4: outstanding = tile(2i+1)(6, staged prev P5-P7) + tile(2i+2)(6) = 12
//       -> certifies tile 2i+1 BEFORE P5's ds_reads (issued after P4's bar).
//   P8: certifies tile 2i+2 before next-iter P1's ds_reads.
// A phase never stages the slot it reads; every WAR is separated by >=1
// barrier; >=6 loads stay in flight (never drains in the loop).
// ---------------------------------------------------------------------------
template<typename OutT>
__global__ __launch_bounds__(512) void gemm8(
    const u16* __restrict__ A,
    const u16* __restrict__ B0, const u16* __restrict__ B1, const u16* __restrict__ B2,
    OutT* __restrict__ C0, OutT* __restrict__ C1, OutT* __restrict__ C2,
    int M, int N, int K)
{
    const int z = blockIdx.z;
    const u16* Bp = (z == 0) ? B0 : (z == 1) ? B1 : B2;
    OutT*      Cp = (z == 0) ? C0 : (z == 1) ? C1 : C2;

    __shared__ short As[3 * 256 * 64];   // 96 KB (3 slots)
    __shared__ short Bs[3 * 128 * 64];   // 48 KB

    const int t    = threadIdx.x;
    const int lane = t & 63;
    const int w    = t >> 6;             // 0..7
    const int wr   = w >> 1;             // 0..3 (64-row band)
    const int wc   = w & 1;              // 0..1 (64-col band)
    const int m0   = blockIdx.x * 256;
    const int n0   = blockIdx.y * 128;

    const int srow = t >> 3;                          // 0..63
    const int scol = (((t & 7) ^ ((t >> 3) & 7)) * 8);

    const u16* gA = A  + (size_t)(m0 + srow) * K + scol;
    const u16* gB = Bp + (size_t)(n0 + srow) * K + scol;
    char* lA = (char*)As + (size_t)w * 1024;          // wave-uniform bases
    char* lB = (char*)Bs + (size_t)w * 1024;
    const size_t rstep = (size_t)64 * K;

    const int fr = lane & 15;
    const int g4 = lane >> 4;
    const int xa = fr & 7;

    f4v acc[4][4];
#pragma unroll
    for (int i = 0; i < 4; i++)
#pragma unroll
        for (int j = 0; j < 4; j++) acc[i][j] = (f4v){0.f, 0.f, 0.f, 0.f};

    // A: 256 rows = 2 half-units (h0 rows 0-127, h1 rows 128-255), 2 gloads
    // each (64 rows / gload). B: 128 rows = 1 unit, 2 gloads.
    auto stageA = [&](int p, int kt, int h) {
        const u16* g = gA + (size_t)kt * 64;
#pragma unroll
        for (int j = 0; j < 2; j++)
            gload_lds16(g + (size_t)(2 * h + j) * rstep,
                        lA + p * 32768 + (2 * h + j) * 8192);
    };
    auto stageB = [&](int p, int kt) {
        const u16* g = gB + (size_t)kt * 64;
#pragma unroll
        for (int j = 0; j < 2; j++)
            gload_lds16(g + (size_t)j * rstep,
                        lB + p * 16384 + j * 8192);
    };
    auto loadA = [&](int p, int mh, int ks, s8v* aF) {
        const short* base = As + p * 16384;
        const int sl = ((ks * 4 + g4) ^ xa) * 8;
#pragma unroll
        for (int j = 0; j < 2; j++)
            aF[j] = *(const s8v*)&base[(wr * 64 + (mh * 2 + j) * 16 + fr) * 64 + sl];
    };
    auto loadB = [&](int p, int ks, s8v* bF) {
        const short* base = Bs + p * 8192;
        const int sl = ((ks * 4 + g4) ^ xa) * 8;
#pragma unroll
        for (int ni = 0; ni < 4; ni++)
            bF[ni] = *(const s8v*)&base[(wc * 64 + ni * 16 + fr) * 64 + sl];
    };
    auto mfc = [&](int mh, s8v* aF, s8v* bF) {
        __builtin_amdgcn_s_setprio(1);
#pragma unroll
        for (int j = 0; j < 2; j++)
#pragma unroll
            for (int ni = 0; ni < 4; ni++)
                acc[mh * 2 + j][ni] = mfma16(aF[j], bF[ni], acc[mh * 2 + j][ni]);
        __builtin_amdgcn_s_setprio(0);
    };

    const int NT = K / 64;               // 32
    const int NI = NT / 2;               // 16

    // prologue: tile0 -> slot0, tile1 -> slot1 (12 loads); certify tile0.
    stageA(0, 0, 0); stageA(0, 0, 1); stageB(0, 0);
    stageA(1, 1, 0); stageA(1, 1, 1); stageB(1, 1);
    VMCNT(6);
    SBAR();

    int s0 = 0, s1 = 1, s2 = 2;
    for (int i = 0; i < NI; i++) {
        const int k2 = (2 * i + 2 < NT) ? 2 * i + 2 : 0;   // clamp: addr valid, unread
        const int k3 = (2 * i + 3 < NT) ? 2 * i + 3 : 1;
        s8v aF[2], bF[4];

        // P1: t0 ks0 mh0
        loadB(s0, 0, bF); loadA(s0, 0, 0, aF);
        stageA(s2, k2, 0);
        SBAR(); mfc(0, aF, bF); SBAR();
        // P2: t0 ks0 mh1 (B reg-reuse)
        loadA(s0, 1, 0, aF);
        stageA(s2, k2, 1);
        SBAR(); mfc(1, aF, bF); SBAR();
        // P3: t0 ks1 mh0
        loadB(s0, 1, bF); loadA(s0, 0, 1, aF);
        stageB(s2, k2);
        SBAR(); mfc(0, aF, bF); SBAR();
        // P4: t0 ks1 mh1 — certify tile 2i+1 (residue: tile 2i+2's 6)
        loadA(s0, 1, 1, aF);
        VMCNT(6); SBAR(); mfc(1, aF, bF); SBAR();
        // P5: t1 ks0 mh0
        loadB(s1, 0, bF); loadA(s1, 0, 0, aF);
        stageA(s0, k3, 0);
        SBAR(); mfc(0, aF, bF); SBAR();
        // P6: t1 ks0 mh1
        loadA(s1, 1, 0, aF);
        stageA(s0, k3, 1);
        SBAR(); mfc(1, aF, bF); SBAR();
        // P7: t1 ks1 mh0
        loadB(s1, 1, bF); loadA(s1, 0, 1, aF);
        stageB(s0, k3);
        SBAR(); mfc(0, aF, bF); SBAR();
        // P8: t1 ks1 mh1 — certify tile 2i+2 (residue: tile 2i+3's 6)
        loadA(s1, 1, 1, aF);
        VMCNT(6); SBAR(); mfc(1, aF, bF); SBAR();

        // rotate: next iter reads tiles 2i+2 (in s2) and 2i+3 (in s0)
        const int ns0 = s2, ns1 = s0, ns2 = s1;
        s0 = ns0; s1 = ns1; s2 = ns2;
    }
    VMCNT(0);

    // epilogue: C row = (lane>>4)*4+reg, col = lane&15 per 16x16 frag
    const int rg = g4 * 4;
#pragma unroll
    for (int mi = 0; mi < 4; mi++)
#pragma unroll
        for (int ni = 0; ni < 4; ni++) {
            size_t base = (size_t)(m0 + wr * 64 + mi * 16 + rg) * N
                        + (n0 + wc * 64 + ni * 16 + fr);
#pragma unroll
            for (int r = 0; r < 4; r++)
                store_out(&Cp[base + (size_t)r * N], acc[mi][ni][r]);
        }
}

// ---------------------------------------------------------------------------
// RoPE in-place on Q and K. Folds (1/sqrt(DK))*log2(e) into Q so attention
// softmax can use exp2 directly.
// ---------------------------------------------------------------------------
__global__ void rope_kernel(u32* __restrict__ Q, u32* __restrict__ Kb,
                            const int* __restrict__ pos, int total, int S)
{
    int idx = blockIdx.x * 256 + threadIdx.x;
    if (idx >= total) return;
    int row = idx >> 10;            // 1024 pairs per row
    int pr  = idx & 1023;
    int i   = pr & 63;              // pair index within head
    int s   = row % S;
    float p    = (float)pos[s];
    float freq = __expf((float)i * -0.14391156831212787f);  // 10000^(-i/64)
    float ang  = p * freq;
    float c = cosf(ang), sn = sinf(ang);

    u32 qp = Q[idx];
    float qe = b2f((u16)(qp & 0xffffu)), qo = b2f((u16)(qp >> 16));
    const float sc = 0.12751919968793342f;  // log2(e)/sqrt(128)
    float qe2 = (qe * c - qo * sn) * sc;
    float qo2 = (qe * sn + qo * c) * sc;
    Q[idx] = (u32)f2b(qe2) | ((u32)f2b(qo2) << 16);

    u32 kp = Kb[idx];
    float ke = b2f((u16)(kp & 0xffffu)), ko = b2f((u16)(kp >> 16));
    float ke2 = ke * c - ko * sn;
    float ko2 = ke * sn + ko * c;
    Kb[idx] = (u32)f2b(ke2) | ((u32)f2b(ko2) << 16);
}

// ---------------------------------------------------------------------------
// V transpose: V [b*S + s][o] -> Vt [b][o][s]
// ---------------------------------------------------------------------------
__global__ __launch_bounds__(256) void transpose_v(
    const u16* __restrict__ V, u16* __restrict__ Vt, int S)
{
    __shared__ short Tl[64 * 72];
    const int t  = threadIdx.x;
    const int s0 = blockIdx.x * 64;
    const int o0 = blockIdx.y * 64;
    const int b  = blockIdx.z;
    const int r  = t >> 3;
    const int c8 = (t & 7) * 8;
#pragma unroll
    for (int i = 0; i < 2; i++) {
        int row = r + i * 32;
        *(s8v*)&Tl[row * 72 + c8] =
            *(const s8v*)(V + ((size_t)b * S + s0 + row) * D_MODEL + o0 + c8);
    }
    __syncthreads();
#pragma unroll
    for (int i = 0; i < 2; i++) {
        int orow = r + i * 32;
        s8v v;
#pragma unroll
        for (int j = 0; j < 8; j++)
            v[j] = Tl[(c8 + j) * 72 + orow];
        *(s8v*)(Vt + ((size_t)b * D_MODEL + o0 + orow) * S + s0 + c8) = v;
    }
}

// ---------------------------------------------------------------------------
// Causal flash attention v5: v3 dataflow, 8 waves x 16 q-rows (512 threads)
// -> 2 waves/SIMD for latency hiding. Same pairing (block = tiles (p,15-p) =
// 34 iters), same dbuf + 1 barrier/iter + T14 prefetch, same swizzles.
// ---------------------------------------------------------------------------
#define AKV 64
#define VP  72
#define PP  72

__global__ __launch_bounds__(512) void attn_kernel(
    const u16* __restrict__ Qg, const u16* __restrict__ Kg,
    const u16* __restrict__ Vtg, u16* __restrict__ Og, int S)
{
    __shared__ short Kbuf[2][64 * 128];    // 32 KB (also O[128][128] staging)
    __shared__ short Vbuf[2][128 * VP];    // 36 KB  V^T tiles [d][kv]
    __shared__ short Ps[8][16 * PP];       // 18 KB  per-wave P [q][kv]

    const int t    = threadIdx.x;
    const int lane = t & 63;
    const int w    = t >> 6;               // 0..7
    const int fr   = lane & 15;
    const int g4   = lane >> 4;
    const int xfr  = (fr & 7) << 3;

    // XCD-bijective decode (grid.x = 256 = 8 pairs x 32 (b,h) groups)
    const int d_ = blockIdx.x;
    const int tt = d_ >> 3;
    const int G  = ((tt & 3) << 3) | (d_ & 7);
    const int p  = tt >> 2;
    const int h  = G & 15;
    const int b  = G >> 4;
    const int ntq = S / 128;               // 16

    const u16* Qb  = Qg + ((size_t)b * S) * D_MODEL + (size_t)h * DK;
    const u16* Kb  = Kg + ((size_t)b * S) * D_MODEL + (size_t)h * DK;
    const u16* Vtb = Vtg + ((size_t)b * D_MODEL + (size_t)h * DK) * S;
    u16*       Ob  = Og + ((size_t)b * S) * D_MODEL + (size_t)h * DK;

    // staging maps (512 threads, 2 chunks each)
    const int krow = t >> 4;               // 0..31 (+32)
    const int kc8  = (t & 15) * 8;
    const int kxor = (krow & 7) << 3;      // (krow+32)&7 == krow&7
    const int vd   = t >> 3;               // 0..63 (+64)
    const int vk8  = (t & 7) * 8;

    const int wq64 = (w >> 2) * 64;        // wave's 64-block within the q-tile

    for (int half = 0; half < 2; half++) {
        const int T   = half ? (ntq - 1 - p) : p;
        const int q0  = T * 128;
        const int nkv = 2 * T + 2;

        // Q frags direct from global (once per half); wave-private 16 q rows
        s8v qf[4];
#pragma unroll
        for (int ks = 0; ks < 4; ks++)
            qf[ks] = *(const s8v*)(Qb +
                (size_t)(q0 + w * 16 + fr) * D_MODEL + ks * 32 + g4 * 8);

        // tile 0 -> regs
        s8v kreg[2], vreg[2];
#pragma unroll
        for (int c = 0; c < 2; c++) {
            kreg[c] = *(const s8v*)(Kb + (size_t)(krow + 32 * c) * D_MODEL + kc8);
            vreg[c] = *(const s8v*)(Vtb + (size_t)(vd + 64 * c) * S + vk8);
        }
        __syncthreads();                   // prev half's O-staging reads done
#pragma unroll
        for (int c = 0; c < 2; c++)
            *(s8v*)&Kbuf[0][(krow + 32 * c) * 128 + (kc8 ^ kxor)] = kreg[c];
#pragma unroll
        for (int c = 0; c < 2; c++)
            *(s8v*)&Vbuf[0][(vd + 64 * c) * VP + vk8] = vreg[c];
        __syncthreads();

        float m_st = -1e30f, l_st = 0.f;
        f4v accO[8];
#pragma unroll
        for (int df = 0; df < 8; df++) accO[df] = (f4v){0.f, 0.f, 0.f, 0.f};
        const int qg = q0 + w * 16 + fr;

        for (int kt = 0; kt < nkv; kt++) {
            const int  kv0  = kt * AKV;
            const int  buf  = kt & 1;
            const bool last = (kt + 1 == nkv);
            const bool act  = (kv0 <= q0 + wq64);   // wave has unmasked kv

            // T14: issue next tile's loads now, consume after compute
            if (!last) {
                const size_t kvn = (size_t)(kt + 1) * AKV;
#pragma unroll
                for (int c = 0; c < 2; c++) {
                    kreg[c] = *(const s8v*)(Kb + (kvn + krow + 32 * c) * D_MODEL + kc8);
                    vreg[c] = *(const s8v*)(Vtb + (size_t)(vd + 64 * c) * S + kvn + vk8);
                }
            }

            if (act) {
                // S^T = K * Q^T : C row = kv, col = q (wave-private 16 q)
                f4v sacc[4];
#pragma unroll
                for (int i = 0; i < 4; i++) sacc[i] = (f4v){0.f, 0.f, 0.f, 0.f};
#pragma unroll
                for (int ks = 0; ks < 4; ks++) {
#pragma unroll
                    for (int kf = 0; kf < 4; kf++) {
                        s8v kfr = *(const s8v*)&Kbuf[buf][(kf * 16 + fr) * 128 +
                                                         ((ks * 32 + g4 * 8) ^ xfr)];
                        sacc[kf] = mfma16(kfr, qf[ks], sacc[kf]);
                    }
                }

                if (kv0 == q0 + wq64) {        // diagonal tile for this wave
#pragma unroll
                    for (int kf = 0; kf < 4; kf++)
#pragma unroll
                        for (int r = 0; r < 4; r++)
                            if (kv0 + kf * 16 + g4 * 4 + r > qg)
                                sacc[kf][r] = -1e30f;
                }
                float rm = -1e30f;
#pragma unroll
                for (int kf = 0; kf < 4; kf++)
                    rm = fmaxf(rm, fmaxf(fmaxf(sacc[kf][0], sacc[kf][1]),
                                         fmaxf(sacc[kf][2], sacc[kf][3])));
                rm = fmaxf(rm, __shfl_xor(rm, 16));
                rm = fmaxf(rm, __shfl_xor(rm, 32));
                if (__any(rm > m_st)) {        // exact defer: P <= 1 otherwise
                    float mn   = fmaxf(m_st, rm);
                    float corr = fexp2(m_st - mn);
                    l_st *= corr;
#pragma unroll
                    for (int df = 0; df < 8; df++) {
                        accO[df][0] *= corr; accO[df][1] *= corr;
                        accO[df][2] *= corr; accO[df][3] *= corr;
                    }
                    m_st = mn;
                }
                float rsum = 0.f;
#pragma unroll
                for (int kf = 0; kf < 4; kf++) {
                    float p0 = fexp2(sacc[kf][0] - m_st);
                    float p1 = fexp2(sacc[kf][1] - m_st);
                    float p2 = fexp2(sacc[kf][2] - m_st);
                    float p3 = fexp2(sacc[kf][3] - m_st);
                    rsum += (p0 + p1) + (p2 + p3);
                    s4v pk;
                    pk[0] = (short)f2b(p0); pk[1] = (short)f2b(p1);
                    pk[2] = (short)f2b(p2); pk[3] = (short)f2b(p3);
                    *(s4v*)&Ps[w][fr * PP + kf * 16 + g4 * 4] = pk;
                }
                rsum += __shfl_xor(rsum, 16);
                rsum += __shfl_xor(rsum, 32);
                l_st += rsum;

                // O^T += V^T * P^T (same-wave Ps RAW ok: DS pipe in-order)
#pragma unroll
                for (int ks = 0; ks < 2; ks++) {
                    s8v pf = *(const s8v*)&Ps[w][fr * PP + ks * 32 + g4 * 8];
#pragma unroll
                    for (int df = 0; df < 8; df++) {
                        s8v vf = *(const s8v*)&Vbuf[buf][(df * 16 + fr) * VP +
                                                         ks * 32 + g4 * 8];
                        accO[df] = mfma16(vf, pf, accO[df]);
                    }
                }
            }

            // write prefetched tile to the other buffer (all waves)
            if (!last) {
#pragma unroll
                for (int c = 0; c < 2; c++)
                    *(s8v*)&Kbuf[buf ^ 1][(krow + 32 * c) * 128 + (kc8 ^ kxor)] = kreg[c];
#pragma unroll
                for (int c = 0; c < 2; c++)
                    *(s8v*)&Vbuf[buf ^ 1][(vd + 64 * c) * VP + vk8] = vreg[c];
            }
            __syncthreads();
        }

        // normalize, transpose O^T -> O through Kbuf ([128][128]), store
        float inv = 1.f / l_st;
        short* OL = (short*)&Kbuf[0][0];
#pragma unroll
        for (int df = 0; df < 8; df++) {
            s4v ov;
            ov[0] = (short)f2b(accO[df][0] * inv);
            ov[1] = (short)f2b(accO[df][1] * inv);
            ov[2] = (short)f2b(accO[df][2] * inv);
            ov[3] = (short)f2b(accO[df][3] * inv);
            *(s4v*)&OL[(w * 16 + fr) * 128 + ((df * 16 + g4 * 4) ^ xfr)] = ov;
        }
        __syncthreads();
#pragma unroll
        for (int i = 0; i < 4; i++) {
            int row = i * 32 + (t >> 4);
            int ch  = (t & 15) * 8;
            s8v v = *(const s8v*)&OL[row * 128 + (ch ^ ((row & 7) << 3))];
            *(s8v*)(Ob + (size_t)(q0 + row) * D_MODEL + ch) = v;
        }
    }
}

// ---------------------------------------------------------------------------
extern "C" void kernel_launch(void* const* d_in, const int* in_sizes, int n_in,
                              void* d_out, int out_size, void* d_ws, size_t ws_size,
                              hipStream_t stream)
{
    const float* x  = (const float*)d_in[0];
    const float* wq = (const float*)d_in[1];
    const float* wk = (const float*)d_in[2];
    const float* wv = (const float*)d_in[3];
    const float* wo = (const float*)d_in[4];
    const int*   tp = (const int*)d_in[5];

    const int S  = in_sizes[5];
    const int BS = in_sizes[0] / D_MODEL;   // B*S rows (4096)
    const int Bn = BS / S;
    const int NW = D_MODEL * D_MODEL;
    const int NX = BS * D_MODEL;

    // ws (u16 elems): [Q][K][V -> O][Xb -> Vt][Wq][Wk][Wv][Wo] = 96 MB
    u16* Qw  = (u16*)d_ws;
    u16* Kw  = Qw + (size_t)NX;
    u16* Vw  = Kw + (size_t)NX;             // V; reused as attention output O
    u16* Xb  = Vw + (size_t)NX;             // x bf16; reused as V^T
    u16* Wqb = Xb + (size_t)NX;
    u16* Wkb = Wqb + (size_t)NW;
    u16* Wvb = Wkb + (size_t)NW;
    u16* Wob = Wvb + (size_t)NW;

    {
        dim3 g((NX / 8 + 255) / 256, 5);
        cvt_bf16<<<g, 256, 0, stream>>>(x, wq, wk, wv, wo,
                                        Xb, Wqb, Wkb, Wvb, Wob, NX, NW);
    }

    // Q,K,V projections: 256x128 8-phase, 16*16*3 = 768 blocks = 3 full rounds
    dim3 gq(BS / 256, D_MODEL / 128, 3);
    gemm8<u16><<<gq, 512, 0, stream>>>(Xb, Wqb, Wkb, Wvb, Qw, Kw, Vw,
                                       BS, D_MODEL, D_MODEL);

    // RoPE on Q,K (in place); V^T into Xb region (x is dead after QKV GEMM)
    int total = BS * (D_MODEL / 2);
    rope_kernel<<<(total + 255) / 256, 256, 0, stream>>>((u32*)Qw, (u32*)Kw, tp, total, S);
    transpose_v<<<dim3(S / 64, D_MODEL / 64, Bn), 256, 0, stream>>>(Vw, Xb, S);

    // causal flash attention: O (bf16) into the V region
    attn_kernel<<<dim3((S / 256) * NH * Bn, 1, 1), 512, 0, stream>>>(Qw, Kw, Xb, Vw, S);

    // output projection -> fp32 d_out: 16*16 = 256 blocks = 1 full round
    dim3 go(BS / 256, D_MODEL / 128, 1);
    gemm8<float><<<go, 512, 0, stream>>>(Vw, Wob, Wob, Wob,
                                         (float*)d_out, (float*)d_out, (float*)d_out,
                                         BS, D_MODEL, D_MODEL);
}

// Round 12
// 237.237 us; speedup vs baseline: 1.3470x; 1.0557x over previous
//
#include <hip/hip_runtime.h>
#include <stdint.h>
#include <stddef.h>

typedef unsigned short u16;
typedef unsigned int u32;
typedef __attribute__((ext_vector_type(8))) short s8v;   // 8 bf16 = one MFMA A/B frag
typedef __attribute__((ext_vector_type(4))) short s4v;
typedef __attribute__((ext_vector_type(4))) float f4v;   // MFMA C/D frag / float4

#define D_MODEL 2048
#define NH 16
#define DK 128

__device__ __forceinline__ float b2f(u16 u) {
    union { u32 i; float f; } v; v.i = ((u32)u) << 16; return v.f;
}
__device__ __forceinline__ u16 f2b(float f) {  // RNE; values here always finite
    u32 u = __builtin_bit_cast(u32, f);
    u32 r = (u + 0x7fffu + ((u >> 16) & 1u)) >> 16;
    return (u16)r;
}
__device__ __forceinline__ float fexp2(float x) {        // native v_exp_f32 (base-2)
    return __builtin_amdgcn_exp2f(x);
}
__device__ __forceinline__ f4v mfma16(s8v a, s8v b, f4v c) {
    return __builtin_amdgcn_mfma_f32_16x16x32_bf16(a, b, c, 0, 0, 0);
}
// async global->LDS, 16B/lane. LDS dest must be the WAVE-UNIFORM base; HW adds lane*16.
__device__ __forceinline__ void gload_lds16(const void* g, void* l) {
    __builtin_amdgcn_global_load_lds(
        (const __attribute__((address_space(1))) u32*)(uintptr_t)g,
        (__attribute__((address_space(3))) u32*)(uintptr_t)l, 16, 0, 0);
}

__device__ __forceinline__ void store_out(u16* p, float v)   { *p = f2b(v); }
__device__ __forceinline__ void store_out(float* p, float v) { *p = v; }

#define SBAR()   asm volatile("s_barrier" ::: "memory")
#define VMCNT(n) asm volatile("s_waitcnt vmcnt(" #n ")" ::: "memory")

// ---------------------------------------------------------------------------
// fp32 -> bf16 conversion pass. grid.y selects segment (0: x, 1..4: weights).
// ---------------------------------------------------------------------------
__global__ __launch_bounds__(256) void cvt_bf16(
    const float* __restrict__ s0, const float* __restrict__ s1,
    const float* __restrict__ s2, const float* __restrict__ s3,
    const float* __restrict__ s4,
    u16* __restrict__ d0, u16* __restrict__ d1, u16* __restrict__ d2,
    u16* __restrict__ d3, u16* __restrict__ d4,
    int n0, int nw)
{
    const int seg = blockIdx.y;
    const float* s = (seg == 0) ? s0 : (seg == 1) ? s1 : (seg == 2) ? s2 : (seg == 3) ? s3 : s4;
    u16*         d = (seg == 0) ? d0 : (seg == 1) ? d1 : (seg == 2) ? d2 : (seg == 3) ? d3 : d4;
    const int    n = (seg == 0) ? n0 : nw;
    int i = (blockIdx.x * 256 + threadIdx.x) * 8;
    if (i >= n) return;
    f4v a = *(const f4v*)(s + i);
    f4v b = *(const f4v*)(s + i + 4);
    s8v o;
    o[0] = (short)f2b(a[0]); o[1] = (short)f2b(a[1]);
    o[2] = (short)f2b(a[2]); o[3] = (short)f2b(a[3]);
    o[4] = (short)f2b(b[0]); o[5] = (short)f2b(b[1]);
    o[6] = (short)f2b(b[2]); o[7] = (short)f2b(b[3]);
    *(s8v*)(d + i) = o;
}

// ---------------------------------------------------------------------------
// GEMM 8-phase 256x256 (m201 geometry): BK=64, 512 thr = 8 waves (2M x 4N,
// wave-tile 128x64 -> 16 MFMA per phase per ~6 ds_reads). LDS 128 KB, 2
// slots. T2 swizzle via pre-swizzled global source + XOR'd frag reads.
// Stage rotation (iter i; t0=2i slot0, t1=2i+1 slot1):
//   P1:B(t1,h1) P2:A(t1,h0) P3:A(t1,h1) P4:B(t0+2,h0)
//   P5:B(t0+2,h1) P6:A(t0+2,h0) P7:A(t0+2,h1) P8:B(t1+2,h0)
// vmcnt placement (AUDIT-FIXED from round 9): P1/P5 = vmcnt(4); P4/P8 =
// vmcnt(2) — at P4 the residue must exclude A(t1,h1) staged at P3 (P5-P7
// read it); at P8 exclude A(t0+2,h1) from P7 (next P1-P4 read it). Each
// phase's ds_reads are protected by the PREVIOUS phase's vmcnt+barrier.
// Grid (16,8,2) = 256 blocks = one perfect CU round (Q and K projections).
// ---------------------------------------------------------------------------
__global__ __launch_bounds__(512) void gemm256(
    const u16* __restrict__ A,
    const u16* __restrict__ B0, const u16* __restrict__ B1,
    u16* __restrict__ C0, u16* __restrict__ C1,
    int M, int N, int K)
{
    const int z = blockIdx.z;
    const u16* Bp = (z == 0) ? B0 : B1;
    u16*       Cp = (z == 0) ? C0 : C1;

    __shared__ short As[2 * 256 * 64];   // 64 KB (2 slots)
    __shared__ short Bs[2 * 256 * 64];   // 64 KB

    const int t    = threadIdx.x;
    const int lane = t & 63;
    const int w    = t >> 6;             // 0..7
    const int wr   = w >> 2;             // 0..1  (128-row band)
    const int wc   = w & 3;              // 0..3  (64-col band)
    const int m0   = blockIdx.x * 256;
    const int n0   = blockIdx.y * 256;

    const int srow = t >> 3;                          // 0..63
    const int scol = (((t & 7) ^ ((t >> 3) & 7)) * 8);

    const u16* gA = A  + (size_t)(m0 + srow) * K + scol;
    const u16* gB = Bp + (size_t)(n0 + srow) * K + scol;
    char* lA = (char*)As + (size_t)w * 1024;          // wave-uniform bases
    char* lB = (char*)Bs + (size_t)w * 1024;
    const size_t rstep = (size_t)64 * K;

    const int fr = lane & 15;
    const int g4 = lane >> 4;
    const int xa = fr & 7;

    f4v acc[8][4];
#pragma unroll
    for (int i = 0; i < 8; i++)
#pragma unroll
        for (int j = 0; j < 4; j++) acc[i][j] = (f4v){0.f, 0.f, 0.f, 0.f};

    auto stageA = [&](int p, int kt, int h) {
        const u16* g = gA + (size_t)kt * 64;
#pragma unroll
        for (int j = 0; j < 2; j++)
            gload_lds16(g + (size_t)(2 * h + j) * rstep,
                        lA + p * 32768 + (2 * h + j) * 8192);
    };
    auto stageB = [&](int p, int kt, int h) {
        const u16* g = gB + (size_t)kt * 64;
#pragma unroll
        for (int j = 0; j < 2; j++)
            gload_lds16(g + (size_t)(2 * h + j) * rstep,
                        lB + p * 32768 + (2 * h + j) * 8192);
    };
    auto loadA = [&](int p, int mh, int ks, s8v* aF) {
        const short* base = As + p * 16384;
        const int sl = ((ks * 4 + g4) ^ xa) * 8;
#pragma unroll
        for (int mi = 0; mi < 4; mi++)
            aF[mi] = *(const s8v*)&base[(wr * 128 + mh * 64 + mi * 16 + fr) * 64 + sl];
    };
    auto loadB = [&](int p, int ks, s8v* bF) {
        const short* base = Bs + p * 16384;
        const int sl = ((ks * 4 + g4) ^ xa) * 8;
#pragma unroll
        for (int ni = 0; ni < 4; ni++)
            bF[ni] = *(const s8v*)&base[(wc * 64 + ni * 16 + fr) * 64 + sl];
    };
    auto mfc = [&](int mh, s8v* aF, s8v* bF) {
        __builtin_amdgcn_s_setprio(1);
#pragma unroll
        for (int mi = 0; mi < 4; mi++)
#pragma unroll
            for (int ni = 0; ni < 4; ni++)
                acc[mh * 4 + mi][ni] = mfma16(aF[mi], bF[ni], acc[mh * 4 + mi][ni]);
        __builtin_amdgcn_s_setprio(0);
    };

    const int NT = K / 64;               // 32
    const int NI = NT / 2;               // 16

    // prologue: full tile 0 (slot 0) + B(1,h0); certify tile 0.
    stageB(0, 0, 0); stageB(0, 0, 1); stageA(0, 0, 0); stageA(0, 0, 1);
    stageB(1, 1, 0);
    VMCNT(2);
    SBAR();

    for (int i = 0; i < NI; i++) {
        const int k1 = 2 * i + 1;
        const int k2 = (2 * i + 2 < NT) ? 2 * i + 2 : 0;   // clamp: addr valid, unread
        const int k3 = (2 * i + 3 < NT) ? 2 * i + 3 : 1;
        s8v aF[4], bF[4];

        // P1: t0 (mh0,ks0)
        loadA(0, 0, 0, aF); loadB(0, 0, bF);
        stageB(1, k1, 1);
        VMCNT(4); SBAR();
        mfc(0, aF, bF);
        SBAR();
        // P2: t0 (mh1,ks0) — B reg-reuse
        loadA(0, 1, 0, aF);
        stageA(1, k1, 0);
        SBAR();
        mfc(1, aF, bF);
        SBAR();
        // P3: t0 (mh0,ks1)
        loadA(0, 0, 1, aF); loadB(0, 1, bF);
        stageA(1, k1, 1);
        SBAR();
        mfc(0, aF, bF);
        SBAR();
        // P4: t0 (mh1,ks1) — vmcnt(2): certify A(t1,h1) (P3) for P5-P7
        loadA(0, 1, 1, aF);
        stageB(0, k2, 0);
        VMCNT(2); SBAR();
        mfc(1, aF, bF);
        SBAR();
        // P5: t1 (mh0,ks0)
        loadA(1, 0, 0, aF); loadB(1, 0, bF);
        stageB(0, k2, 1);
        VMCNT(4); SBAR();
        mfc(0, aF, bF);
        SBAR();
        // P6: t1 (mh1,ks0)
        loadA(1, 1, 0, aF);
        stageA(0, k2, 0);
        SBAR();
        mfc(1, aF, bF);
        SBAR();
        // P7: t1 (mh0,ks1)
        loadA(1, 0, 1, aF); loadB(1, 1, bF);
        stageA(0, k2, 1);
        SBAR();
        mfc(0, aF, bF);
        SBAR();
        // P8: t1 (mh1,ks1) — vmcnt(2): certify A(t0+2,h1) (P7) for next P1-P4
        loadA(1, 1, 1, aF);
        stageB(1, k3, 0);
        VMCNT(2); SBAR();
        mfc(1, aF, bF);
        SBAR();
    }
    VMCNT(0);

    // epilogue: C row = (lane>>4)*4+reg, col = lane&15 per 16x16 frag
    const int rg = g4 * 4;
#pragma unroll
    for (int mit = 0; mit < 8; mit++)
#pragma unroll
        for (int ni = 0; ni < 4; ni++) {
            size_t base = (size_t)(m0 + wr * 128 + mit * 16 + rg) * N
                        + (n0 + wc * 64 + ni * 16 + fr);
#pragma unroll
            for (int r = 0; r < 4; r++)
                Cp[base + (size_t)r * N] = f2b(acc[mit][ni][r]);
        }
}

// ---------------------------------------------------------------------------
// GEMM 8-phase 256x128 3-slot (round-11, passed): BK=64, 512 thr = 8 waves
// (4M x 2N, 64x64 wave-tile). LDS 144 KB. Schedule/audit unchanged from r11.
// MODE 0: direct store C[m][n] (OutT = float or u16).
// MODE 1: V^T epilogue — acc transposed through LDS (pad-264) and stored as
//         Vt[b][o][s] (o = n, s = m mod Sdim). OutT must be u16.
// ---------------------------------------------------------------------------
template<typename OutT, int MODE>
__global__ __launch_bounds__(512) void gemm128(
    const u16* __restrict__ A, const u16* __restrict__ Bp,
    OutT* __restrict__ Cp, int M, int N, int K, int Sdim)
{
    __shared__ short As[3 * 256 * 64];   // 96 KB (3 slots; also V^T staging)
    __shared__ short Bs[3 * 128 * 64];   // 48 KB

    const int t    = threadIdx.x;
    const int lane = t & 63;
    const int w    = t >> 6;             // 0..7
    const int wr   = w >> 1;             // 0..3 (64-row band)
    const int wc   = w & 1;              // 0..1 (64-col band)
    const int m0   = blockIdx.x * 256;
    const int n0   = blockIdx.y * 128;

    const int srow = t >> 3;                          // 0..63
    const int scol = (((t & 7) ^ ((t >> 3) & 7)) * 8);

    const u16* gA = A  + (size_t)(m0 + srow) * K + scol;
    const u16* gB = Bp + (size_t)(n0 + srow) * K + scol;
    char* lA = (char*)As + (size_t)w * 1024;          // wave-uniform bases
    char* lB = (char*)Bs + (size_t)w * 1024;
    const size_t rstep = (size_t)64 * K;

    const int fr = lane & 15;
    const int g4 = lane >> 4;
    const int xa = fr & 7;

    f4v acc[4][4];
#pragma unroll
    for (int i = 0; i < 4; i++)
#pragma unroll
        for (int j = 0; j < 4; j++) acc[i][j] = (f4v){0.f, 0.f, 0.f, 0.f};

    auto stageA = [&](int p, int kt, int h) {
        const u16* g = gA + (size_t)kt * 64;
#pragma unroll
        for (int j = 0; j < 2; j++)
            gload_lds16(g + (size_t)(2 * h + j) * rstep,
                        lA + p * 32768 + (2 * h + j) * 8192);
    };
    auto stageB = [&](int p, int kt) {
        const u16* g = gB + (size_t)kt * 64;
#pragma unroll
        for (int j = 0; j < 2; j++)
            gload_lds16(g + (size_t)j * rstep,
                        lB + p * 16384 + j * 8192);
    };
    auto loadA = [&](int p, int mh, int ks, s8v* aF) {
        const short* base = As + p * 16384;
        const int sl = ((ks * 4 + g4) ^ xa) * 8;
#pragma unroll
        for (int j = 0; j < 2; j++)
            aF[j] = *(const s8v*)&base[(wr * 64 + (mh * 2 + j) * 16 + fr) * 64 + sl];
    };
    auto loadB = [&](int p, int ks, s8v* bF) {
        const short* base = Bs + p * 8192;
        const int sl = ((ks * 4 + g4) ^ xa) * 8;
#pragma unroll
        for (int ni = 0; ni < 4; ni++)
            bF[ni] = *(const s8v*)&base[(wc * 64 + ni * 16 + fr) * 64 + sl];
    };
    auto mfc = [&](int mh, s8v* aF, s8v* bF) {
        __builtin_amdgcn_s_setprio(1);
#pragma unroll
        for (int j = 0; j < 2; j++)
#pragma unroll
            for (int ni = 0; ni < 4; ni++)
                acc[mh * 2 + j][ni] = mfma16(aF[j], bF[ni], acc[mh * 2 + j][ni]);
        __builtin_amdgcn_s_setprio(0);
    };

    const int NT = K / 64;               // 32
    const int NI = NT / 2;               // 16

    stageA(0, 0, 0); stageA(0, 0, 1); stageB(0, 0);
    stageA(1, 1, 0); stageA(1, 1, 1); stageB(1, 1);
    VMCNT(6);
    SBAR();

    int s0 = 0, s1 = 1, s2 = 2;
    for (int i = 0; i < NI; i++) {
        const int k2 = (2 * i + 2 < NT) ? 2 * i + 2 : 0;
        const int k3 = (2 * i + 3 < NT) ? 2 * i + 3 : 1;
        s8v aF[2], bF[4];

        // P1
        loadB(s0, 0, bF); loadA(s0, 0, 0, aF);
        stageA(s2, k2, 0);
        SBAR(); mfc(0, aF, bF); SBAR();
        // P2
        loadA(s0, 1, 0, aF);
        stageA(s2, k2, 1);
        SBAR(); mfc(1, aF, bF); SBAR();
        // P3
        loadB(s0, 1, bF); loadA(s0, 0, 1, aF);
        stageB(s2, k2);
        SBAR(); mfc(0, aF, bF); SBAR();
        // P4 — certify tile 2i+1 (residue: tile 2i+2's 6)
        loadA(s0, 1, 1, aF);
        VMCNT(6); SBAR(); mfc(1, aF, bF); SBAR();
        // P5
        loadB(s1, 0, bF); loadA(s1, 0, 0, aF);
        stageA(s0, k3, 0);
        SBAR(); mfc(0, aF, bF); SBAR();
        // P6
        loadA(s1, 1, 0, aF);
        stageA(s0, k3, 1);
        SBAR(); mfc(1, aF, bF); SBAR();
        // P7
        loadB(s1, 1, bF); loadA(s1, 0, 1, aF);
        stageB(s0, k3);
        SBAR(); mfc(0, aF, bF); SBAR();
        // P8 — certify tile 2i+2 (residue: tile 2i+3's 6)
        loadA(s1, 1, 1, aF);
        VMCNT(6); SBAR(); mfc(1, aF, bF); SBAR();

        const int ns0 = s2, ns1 = s0, ns2 = s1;
        s0 = ns0; s1 = ns1; s2 = ns2;
    }
    VMCNT(0);

    const int rg = g4 * 4;
    if constexpr (MODE == 0) {
#pragma unroll
        for (int mi = 0; mi < 4; mi++)
#pragma unroll
            for (int ni = 0; ni < 4; ni++) {
                size_t base = (size_t)(m0 + wr * 64 + mi * 16 + rg) * N
                            + (n0 + wc * 64 + ni * 16 + fr);
#pragma unroll
                for (int r = 0; r < 4; r++)
                    store_out(&Cp[base + (size_t)r * N], acc[mi][ni][r]);
            }
    } else {
        // V^T epilogue: OT[o 0..127][s 0..255], stride 264 (2-way bank max).
        __syncthreads();                 // all loop LDS reads complete
        short* OT = As;
        const int OP = 264;
#pragma unroll
        for (int mi = 0; mi < 4; mi++)
#pragma unroll
            for (int ni = 0; ni < 4; ni++) {
                s4v pk;
                pk[0] = (short)f2b(acc[mi][ni][0]);
                pk[1] = (short)f2b(acc[mi][ni][1]);
                pk[2] = (short)f2b(acc[mi][ni][2]);
                pk[3] = (short)f2b(acc[mi][ni][3]);
                *(s4v*)&OT[(wc * 64 + ni * 16 + fr) * OP + (wr * 64 + mi * 16 + rg)] = pk;
            }
        __syncthreads();
        const int bb = m0 / Sdim;        // batch (m-range never straddles)
        const int sb = m0 % Sdim;
        u16* Vt = (u16*)Cp;
#pragma unroll
        for (int ps = 0; ps < 8; ps++) {
            int idx  = ps * 512 + t;
            int orow = idx >> 5;         // 0..127
            int sc8  = (idx & 31) * 8;   // 0..248
            s8v v = *(const s8v*)&OT[orow * OP + sc8];
            *(s8v*)(Vt + ((size_t)bb * D_MODEL + n0 + orow) * Sdim + sb + sc8) = v;
        }
    }
}

// ---------------------------------------------------------------------------
// RoPE in-place on Q and K. Folds (1/sqrt(DK))*log2(e) into Q so attention
// softmax can use exp2 directly.
// ---------------------------------------------------------------------------
__global__ void rope_kernel(u32* __restrict__ Q, u32* __restrict__ Kb,
                            const int* __restrict__ pos, int total, int S)
{
    int idx = blockIdx.x * 256 + threadIdx.x;
    if (idx >= total) return;
    int row = idx >> 10;            // 1024 pairs per row
    int pr  = idx & 1023;
    int i   = pr & 63;              // pair index within head
    int s   = row % S;
    float p    = (float)pos[s];
    float freq = __expf((float)i * -0.14391156831212787f);  // 10000^(-i/64)
    float ang  = p * freq;
    float c = cosf(ang), sn = sinf(ang);

    u32 qp = Q[idx];
    float qe = b2f((u16)(qp & 0xffffu)), qo = b2f((u16)(qp >> 16));
    const float sc = 0.12751919968793342f;  // log2(e)/sqrt(128)
    float qe2 = (qe * c - qo * sn) * sc;
    float qo2 = (qe * sn + qo * c) * sc;
    Q[idx] = (u32)f2b(qe2) | ((u32)f2b(qo2) << 16);

    u32 kp = Kb[idx];
    float ke = b2f((u16)(kp & 0xffffu)), ko = b2f((u16)(kp >> 16));
    float ke2 = ke * c - ko * sn;
    float ko2 = ke * sn + ko * c;
    Kb[idx] = (u32)f2b(ke2) | ((u32)f2b(ko2) << 16);
}

// ---------------------------------------------------------------------------
// Causal flash attention v5 (round-11, passed, unchanged): 8 waves x 16 q.
// ---------------------------------------------------------------------------
#define AKV 64
#define VP  72
#define PP  72

__global__ __launch_bounds__(512) void attn_kernel(
    const u16* __restrict__ Qg, const u16* __restrict__ Kg,
    const u16* __restrict__ Vtg, u16* __restrict__ Og, int S)
{
    __shared__ short Kbuf[2][64 * 128];    // 32 KB (also O[128][128] staging)
    __shared__ short Vbuf[2][128 * VP];    // 36 KB  V^T tiles [d][kv]
    __shared__ short Ps[8][16 * PP];       // 18 KB  per-wave P [q][kv]

    const int t    = threadIdx.x;
    const int lane = t & 63;
    const int w    = t >> 6;               // 0..7
    const int fr   = lane & 15;
    const int g4   = lane >> 4;
    const int xfr  = (fr & 7) << 3;

    const int d_ = blockIdx.x;
    const int tt = d_ >> 3;
    const int G  = ((tt & 3) << 3) | (d_ & 7);
    const int p  = tt >> 2;
    const int h  = G & 15;
    const int b  = G >> 4;
    const int ntq = S / 128;               // 16

    const u16* Qb  = Qg + ((size_t)b * S) * D_MODEL + (size_t)h * DK;
    const u16* Kb  = Kg + ((size_t)b * S) * D_MODEL + (size_t)h * DK;
    const u16* Vtb = Vtg + ((size_t)b * D_MODEL + (size_t)h * DK) * S;
    u16*       Ob  = Og + ((size_t)b * S) * D_MODEL + (size_t)h * DK;

    const int krow = t >> 4;               // 0..31 (+32)
    const int kc8  = (t & 15) * 8;
    const int kxor = (krow & 7) << 3;
    const int vd   = t >> 3;               // 0..63 (+64)
    const int vk8  = (t & 7) * 8;

    const int wq64 = (w >> 2) * 64;

    for (int half = 0; half < 2; half++) {
        const int T   = half ? (ntq - 1 - p) : p;
        const int q0  = T * 128;
        const int nkv = 2 * T + 2;

        s8v qf[4];
#pragma unroll
        for (int ks = 0; ks < 4; ks++)
            qf[ks] = *(const s8v*)(Qb +
                (size_t)(q0 + w * 16 + fr) * D_MODEL + ks * 32 + g4 * 8);

        s8v kreg[2], vreg[2];
#pragma unroll
        for (int c = 0; c < 2; c++) {
            kreg[c] = *(const s8v*)(Kb + (size_t)(krow + 32 * c) * D_MODEL + kc8);
            vreg[c] = *(const s8v*)(Vtb + (size_t)(vd + 64 * c) * S + vk8);
        }
        __syncthreads();
#pragma unroll
        for (int c = 0; c < 2; c++)
            *(s8v*)&Kbuf[0][(krow + 32 * c) * 128 + (kc8 ^ kxor)] = kreg[c];
#pragma unroll
        for (int c = 0; c < 2; c++)
            *(s8v*)&Vbuf[0][(vd + 64 * c) * VP + vk8] = vreg[c];
        __syncthreads();

        float m_st = -1e30f, l_st = 0.f;
        f4v accO[8];
#pragma unroll
        for (int df = 0; df < 8; df++) accO[df] = (f4v){0.f, 0.f, 0.f, 0.f};
        const int qg = q0 + w * 16 + fr;

        for (int kt = 0; kt < nkv; kt++) {
            const int  kv0  = kt * AKV;
            const int  buf  = kt & 1;
            const bool last = (kt + 1 == nkv);
            const bool act  = (kv0 <= q0 + wq64);

            if (!last) {
                const size_t kvn = (size_t)(kt + 1) * AKV;
#pragma unroll
                for (int c = 0; c < 2; c++) {
                    kreg[c] = *(const s8v*)(Kb + (kvn + krow + 32 * c) * D_MODEL + kc8);
                    vreg[c] = *(const s8v*)(Vtb + (size_t)(vd + 64 * c) * S + kvn + vk8);
                }
            }

            if (act) {
                f4v sacc[4];
#pragma unroll
                for (int i = 0; i < 4; i++) sacc[i] = (f4v){0.f, 0.f, 0.f, 0.f};
#pragma unroll
                for (int ks = 0; ks < 4; ks++) {
#pragma unroll
                    for (int kf = 0; kf < 4; kf++) {
                        s8v kfr = *(const s8v*)&Kbuf[buf][(kf * 16 + fr) * 128 +
                                                         ((ks * 32 + g4 * 8) ^ xfr)];
                        sacc[kf] = mfma16(kfr, qf[ks], sacc[kf]);
                    }
                }

                if (kv0 == q0 + wq64) {
#pragma unroll
                    for (int kf = 0; kf < 4; kf++)
#pragma unroll
                        for (int r = 0; r < 4; r++)
                            if (kv0 + kf * 16 + g4 * 4 + r > qg)
                                sacc[kf][r] = -1e30f;
                }
                float rm = -1e30f;
#pragma unroll
                for (int kf = 0; kf < 4; kf++)
                    rm = fmaxf(rm, fmaxf(fmaxf(sacc[kf][0], sacc[kf][1]),
                                         fmaxf(sacc[kf][2], sacc[kf][3])));
                rm = fmaxf(rm, __shfl_xor(rm, 16));
                rm = fmaxf(rm, __shfl_xor(rm, 32));
                if (__any(rm > m_st)) {
                    float mn   = fmaxf(m_st, rm);
                    float corr = fexp2(m_st - mn);
                    l_st *= corr;
#pragma unroll
                    for (int df = 0; df < 8; df++) {
                        accO[df][0] *= corr; accO[df][1] *= corr;
                        accO[df][2] *= corr; accO[df][3] *= corr;
                    }
                    m_st = mn;
                }
                float rsum = 0.f;
#pragma unroll
                for (int kf = 0; kf < 4; kf++) {
                    float p0 = fexp2(sacc[kf][0] - m_st);
                    float p1 = fexp2(sacc[kf][1] - m_st);
                    float p2 = fexp2(sacc[kf][2] - m_st);
                    float p3 = fexp2(sacc[kf][3] - m_st);
                    rsum += (p0 + p1) + (p2 + p3);
                    s4v pk;
                    pk[0] = (short)f2b(p0); pk[1] = (short)f2b(p1);
                    pk[2] = (short)f2b(p2); pk[3] = (short)f2b(p3);
                    *(s4v*)&Ps[w][fr * PP + kf * 16 + g4 * 4] = pk;
                }
                rsum += __shfl_xor(rsum, 16);
                rsum += __shfl_xor(rsum, 32);
                l_st += rsum;

#pragma unroll
                for (int ks = 0; ks < 2; ks++) {
                    s8v pf = *(const s8v*)&Ps[w][fr * PP + ks * 32 + g4 * 8];
#pragma unroll
                    for (int df = 0; df < 8; df++) {
                        s8v vf = *(const s8v*)&Vbuf[buf][(df * 16 + fr) * VP +
                                                         ks * 32 + g4 * 8];
                        accO[df] = mfma16(vf, pf, accO[df]);
                    }
                }
            }

            if (!last) {
#pragma unroll
                for (int c = 0; c < 2; c++)
                    *(s8v*)&Kbuf[buf ^ 1][(krow + 32 * c) * 128 + (kc8 ^ kxor)] = kreg[c];
#pragma unroll
                for (int c = 0; c < 2; c++)
                    *(s8v*)&Vbuf[buf ^ 1][(vd + 64 * c) * VP + vk8] = vreg[c];
            }
            __syncthreads();
        }

        float inv = 1.f / l_st;
        short* OL = (short*)&Kbuf[0][0];
#pragma unroll
        for (int df = 0; df < 8; df++) {
            s4v ov;
            ov[0] = (short)f2b(accO[df][0] * inv);
            ov[1] = (short)f2b(accO[df][1] * inv);
            ov[2] = (short)f2b(accO[df][2] * inv);
            ov[3] = (short)f2b(accO[df][3] * inv);
            *(s4v*)&OL[(w * 16 + fr) * 128 + ((df * 16 + g4 * 4) ^ xfr)] = ov;
        }
        __syncthreads();
#pragma unroll
        for (int i = 0; i < 4; i++) {
            int row = i * 32 + (t >> 4);
            int ch  = (t & 15) * 8;
            s8v v = *(const s8v*)&OL[row * 128 + (ch ^ ((row & 7) << 3))];
            *(s8v*)(Ob + (size_t)(q0 + row) * D_MODEL + ch) = v;
        }
    }
}

// ---------------------------------------------------------------------------
extern "C" void kernel_launch(void* const* d_in, const int* in_sizes, int n_in,
                              void* d_out, int out_size, void* d_ws, size_t ws_size,
                              hipStream_t stream)
{
    const float* x  = (const float*)d_in[0];
    const float* wq = (const float*)d_in[1];
    const float* wk = (const float*)d_in[2];
    const float* wv = (const float*)d_in[3];
    const float* wo = (const float*)d_in[4];
    const int*   tp = (const int*)d_in[5];

    const int S  = in_sizes[5];
    const int BS = in_sizes[0] / D_MODEL;   // B*S rows (4096)
    const int Bn = BS / S;
    const int NW = D_MODEL * D_MODEL;
    const int NX = BS * D_MODEL;

    // ws (u16 elems): [Q][K][Vt][Xb -> O][Wq][Wk][Wv][Wo] = 96 MB
    //   Vw holds V^T (written directly by V-GEMM's transposed epilogue);
    //   Xb holds x-bf16, reused for attention output O after V-GEMM.
    u16* Qw  = (u16*)d_ws;
    u16* Kw  = Qw + (size_t)NX;
    u16* Vw  = Kw + (size_t)NX;
    u16* Xb  = Vw + (size_t)NX;
    u16* Wqb = Xb + (size_t)NX;
    u16* Wkb = Wqb + (size_t)NW;
    u16* Wvb = Wkb + (size_t)NW;
    u16* Wob = Wvb + (size_t)NW;

    {
        dim3 g((NX / 8 + 255) / 256, 5);
        cvt_bf16<<<g, 256, 0, stream>>>(x, wq, wk, wv, wo,
                                        Xb, Wqb, Wkb, Wvb, Wob, NX, NW);
    }

    // Q,K projections: 256x256 8-phase, (16,8,2) = 256 blocks = 1 full round
    dim3 gqk(BS / 256, D_MODEL / 256, 2);
    gemm256<<<gqk, 512, 0, stream>>>(Xb, Wqb, Wkb, Qw, Kw, BS, D_MODEL, D_MODEL);

    // V projection with fused V^T epilogue: (16,16) = 256 blocks = 1 round
    dim3 gv(BS / 256, D_MODEL / 128, 1);
    gemm128<u16, 1><<<gv, 512, 0, stream>>>(Xb, Wvb, Vw, BS, D_MODEL, D_MODEL, S);

    // RoPE on Q,K (in place)
    int total = BS * (D_MODEL / 2);
    rope_kernel<<<(total + 255) / 256, 256, 0, stream>>>((u32*)Qw, (u32*)Kw, tp, total, S);

    // causal flash attention: O (bf16) into Xb (x dead after V-GEMM)
    attn_kernel<<<dim3((S / 256) * NH * Bn, 1, 1), 512, 0, stream>>>(Qw, Kw, Vw, Xb, S);

    // output projection -> fp32 d_out: (16,16) = 256 blocks = 1 round
    dim3 go(BS / 256, D_MODEL / 128, 1);
    gemm128<float, 0><<<go, 512, 0, stream>>>(Xb, Wob, (float*)d_out,
                                              BS, D_MODEL, D_MODEL, S);
}